// Round 10
// baseline (256.981 us; speedup 1.0000x reference)
//
#include <hip/hip_runtime.h>
#include <hip/hip_bf16.h>
#include <math.h>

typedef short short8 __attribute__((ext_vector_type(8)));
typedef float f32x4 __attribute__((ext_vector_type(4)));

// ---- problem dims (fixed by setup_inputs) ----
#define BTN   128            // b*t
#define HWN   196            // 14*14
#define CCH   1024
#define NPIX  (BTN * HWN)    // 25088
#define BTSTR (CCH * HWN)    // 200704 floats per bt slab

// ---- workspace layout (bytes) ----
#define WS_D  0                      // d matrix bf16 [NPIX][1024]
#define WS_BW 51380224               // conv_w bf16 [1024][1024]

// ---- complex helpers ----
__device__ __forceinline__ float2 cadd(float2 a, float2 b) { return make_float2(a.x + b.x, a.y + b.y); }
__device__ __forceinline__ float2 csub(float2 a, float2 b) { return make_float2(a.x - b.x, a.y - b.y); }
__device__ __forceinline__ float2 cmulf(float2 a, float2 b) {
  return make_float2(a.x * b.x - a.y * b.y, a.x * b.y + a.y * b.x);
}
__device__ __forceinline__ float2 cmulc(float2 a, float2 b) {   // a * conj(b)
  return make_float2(a.x * b.x + a.y * b.y, a.y * b.x - a.x * b.y);
}
__device__ __forceinline__ float2 csqr(float2 a) {
  return make_float2(a.x * a.x - a.y * a.y, 2.f * a.x * a.y);
}
__device__ __forceinline__ float2 cneg(float2 a) { return make_float2(-a.x, -a.y); }
__device__ __forceinline__ unsigned short f2bf(float f) {   // RNE fp32->bf16
  unsigned u = __float_as_uint(f);
  unsigned r = (u + 0x7fffu + ((u >> 16) & 1u)) >> 16;
  return (unsigned short)r;
}

// ---------------------------------------------------------------- W -> bf16
__global__ void wcast_kernel(const float* __restrict__ w, unsigned short* __restrict__ o) {
  int i = (blockIdx.x * 256 + threadIdx.x) * 4;
  float4 v = *(const float4*)(w + i);
  uint2 u;
  u.x = (unsigned)f2bf(v.x) | ((unsigned)f2bf(v.y) << 16);
  u.y = (unsigned)f2bf(v.z) | ((unsigned)f2bf(v.w) << 16);
  *(uint2*)(o + i) = u;
}

// ---------------------------------------------------------------- stage 1: FFT filter
// R3/R5 version verbatim (proven ~78us).
#define TS 1028   // tile row stride in floats: 1028 % 32 == 4 -> 2-way on stage writes

__global__ __launch_bounds__(256) void fft_filter_kernel(
    const float* __restrict__ x, const float* __restrict__ wfilt,
    unsigned short* __restrict__ dmat) {
  __shared__ float tile[8 * TS];
  __shared__ float2 tw10s[257];
  int tid = threadIdx.x;
  int l = tid & 63, w = tid >> 6;

  for (int i = tid; i < 257; i += 256) {
    float s, c;
    __sincosf(-6.283185307179586f * (float)i / 1024.0f, &s, &c);
    tw10s[i] = make_float2(c, s);
  }

  int blk = (blockIdx.x & 7) * 392 + (blockIdx.x >> 3);   // 3136 = 8 * 392
  int p_base = blk * 8;

  {
    int g = tid & 1, chb = tid >> 1;
    int p = p_base + 4 * g;
    int bt = p / HWN, hw = p - bt * HWN;          // hw%4==0, group stays in row
    const float* src = x + (size_t)bt * BTSTR + hw;
    float* rowb = tile + (4 * g) * TS;
#pragma unroll
    for (int it = 0; it < 8; ++it) {
      int c = chb + 128 * it;
      float4 v = *(const float4*)(src + (size_t)c * HWN);
      float* b = rowb + c;
      b[0 * TS] = v.x; b[1 * TS] = v.y; b[2 * TS] = v.z; b[3 * TS] = v.w;
    }
  }
  __syncthreads();

  const float H = 0.70710678118654752f;
  float2 Wl;
  { float s, c; __sincosf(-6.283185307179586f * (float)l / 512.0f, &s, &c); Wl = make_float2(c, s); }
  float2 W2l = csqr(Wl), W4l = csqr(W2l);
  float2 W2li = make_float2(W2l.y, -W2l.x);
  float2 T01 = cmulf(Wl, make_float2(H, -H));
  float2 T02 = make_float2(Wl.y, -Wl.x);
  float2 T03 = cmulf(Wl, make_float2(-H, -H));
  float2 t3 = csqr(W4l); if (l & 32) t3 = cneg(t3);
  float2 t4 = csqr(t3);  if (l & 16) t4 = cneg(t4);
  float2 t5 = csqr(t4);  if (l & 8)  t5 = cneg(t5);
  float2 t6 = csqr(t5);  if (l & 4)  t6 = cneg(t6);
  float2 t7 = csqr(t6);  if (l & 2)  t7 = cneg(t7);

#pragma unroll 1
  for (int pp = 0; pp < 2; ++pp) {
    int px = w * 2 + pp;
    int p = p_base + px;
    int bt = p / HWN, hw = p - bt * HWN;
    float2* zrow = (float2*)(tile + px * TS);

    float2 zr[8];
#pragma unroll
    for (int r = 0; r < 8; ++r) zr[r] = zrow[l + 64 * r];

    {
      float2 T0[4] = {Wl, T01, T02, T03};
#pragma unroll
      for (int r = 0; r < 4; ++r) {
        float2 a = zr[r], b = zr[r + 4];
        zr[r] = cadd(a, b);
        zr[r + 4] = cmulf(csub(a, b), T0[r]);
      }
    }
#pragma unroll
    for (int h = 0; h < 2; ++h) {
      int b0 = h * 4;
      float2 a = zr[b0], b = zr[b0 + 2];
      zr[b0] = cadd(a, b); zr[b0 + 2] = cmulf(csub(a, b), W2l);
      a = zr[b0 + 1]; b = zr[b0 + 3];
      zr[b0 + 1] = cadd(a, b); zr[b0 + 3] = cmulf(csub(a, b), W2li);
    }
#pragma unroll
    for (int r = 0; r < 8; r += 2) {
      float2 a = zr[r], b = zr[r + 1];
      zr[r] = cadd(a, b); zr[r + 1] = cmulf(csub(a, b), W4l);
    }
    {
      float2 tws[6] = {t3, t4, t5, t6, t7, make_float2(1.f, 0.f)};
      int masks[6] = {32, 16, 8, 4, 2, 1};
#pragma unroll
      for (int s = 0; s < 6; ++s) {
        int m = masks[s];
        bool up = (l & m) != 0;
        float2 te = up ? tws[s] : make_float2(1.f, 0.f);
#pragma unroll
        for (int r = 0; r < 8; ++r) {
          float2 v = zr[r];
          float2 o = make_float2(__shfl_xor(v.x, m, 64), __shfl_xor(v.y, m, 64));
          float2 d = up ? csub(o, v) : cadd(v, o);
          zr[r] = cmulf(d, te);
        }
      }
    }

#pragma unroll
    for (int r = 0; r < 8; ++r) zrow[l + 64 * r] = zr[r];
    {
      float2* z = zrow;
      const float* wf = wfilt + (size_t)((bt & 7) * HWN + hw) * 1026;
      const float sc = 1.0f / 512.0f;
#pragma unroll
      for (int i = 0; i < 4; ++i) {
        int f = 64 * i + l;
        if (f == 0) {
          float2 z0 = z[0];
          float X0 = z0.x + z0.y, X512 = z0.x - z0.y;
          float Y0 = X0 * wf[0] * sc;
          float Y512 = X512 * wf[1024] * sc;
          z[0] = make_float2(0.5f * (Y0 + Y512), 0.5f * (Y0 - Y512));
          float2 z2 = z[1];
          float2 X256 = make_float2(z2.x, -z2.y);
          float2 Y = cmulf(X256, make_float2(wf[512], wf[513]));
          z[1] = make_float2(Y.x * sc, -Y.y * sc);
        } else {
          int g = 512 - f;
          int pf = (int)(__brev((unsigned)f) >> 23);
          int pg = (int)(__brev((unsigned)g) >> 23);
          float2 Zf = z[pf], Zg = z[pg];
          float2 A = make_float2(0.5f * (Zf.x + Zg.x), 0.5f * (Zf.y - Zg.y));
          float2 B = make_float2(0.5f * (Zf.y + Zg.y), -0.5f * (Zf.x - Zg.x));
          float2 Wf = tw10s[f];
          float2 WB = cmulf(Wf, B);
          float2 Xf = make_float2(A.x + WB.x, A.y + WB.y);
          float2 Xg = make_float2(A.x - WB.x, -(A.y - WB.y));
          float2 Yf = cmulf(Xf, make_float2(wf[2 * f], wf[2 * f + 1]));
          float2 Yg = cmulf(Xg, make_float2(wf[2 * g], wf[2 * g + 1]));
          Yf.x *= sc; Yf.y *= sc; Yg.x *= sc; Yg.y *= sc;
          float2 Ap = make_float2(0.5f * (Yf.x + Yg.x), 0.5f * (Yf.y - Yg.y));
          float2 T  = make_float2(0.5f * (Yf.x - Yg.x), 0.5f * (Yf.y + Yg.y));
          float2 Bp = cmulf(make_float2(Wf.x, -Wf.y), T);
          z[pf] = make_float2(Ap.x - Bp.y, Ap.y + Bp.x);
          z[pg] = make_float2(Ap.x + Bp.y, Bp.x - Ap.y);
        }
      }
    }
#pragma unroll
    for (int r = 0; r < 8; ++r) zr[r] = zrow[l + 64 * r];

    {
      float2 tws[6] = {make_float2(1.f, 0.f), t7, t6, t5, t4, t3};
      int masks[6] = {1, 2, 4, 8, 16, 32};
#pragma unroll
      for (int s = 0; s < 6; ++s) {
        int m = masks[s];
        bool up = (l & m) != 0;
        float2 te = up ? make_float2(tws[s].x, -tws[s].y) : make_float2(1.f, 0.f);
#pragma unroll
        for (int r = 0; r < 8; ++r) {
          float2 v = cmulf(zr[r], te);
          float2 o = make_float2(__shfl_xor(v.x, m, 64), __shfl_xor(v.y, m, 64));
          zr[r] = up ? csub(o, v) : cadd(v, o);
        }
      }
    }
#pragma unroll
    for (int r = 0; r < 8; r += 2) {
      float2 v = cmulc(zr[r + 1], W4l);
      float2 a = zr[r];
      zr[r] = cadd(a, v); zr[r + 1] = csub(a, v);
    }
#pragma unroll
    for (int h = 0; h < 2; ++h) {
      int b0 = h * 4;
      float2 v = cmulc(zr[b0 + 2], W2l);
      float2 a = zr[b0];
      zr[b0] = cadd(a, v); zr[b0 + 2] = csub(a, v);
      v = cmulc(zr[b0 + 3], W2li);
      a = zr[b0 + 1];
      zr[b0 + 1] = cadd(a, v); zr[b0 + 3] = csub(a, v);
    }
    {
      float2 T0[4] = {Wl, T01, T02, T03};
#pragma unroll
      for (int r = 0; r < 4; ++r) {
        float2 v = cmulc(zr[r + 4], T0[r]);
        float2 a = zr[r];
        zr[r] = cadd(a, v); zr[r + 4] = csub(a, v);
      }
    }

    unsigned* dst = (unsigned*)(dmat + (size_t)p * CCH);
#pragma unroll
    for (int r = 0; r < 8; ++r) {
      float2 v = zr[r];
      dst[l + 64 * r] = (unsigned)f2bf(v.x) | ((unsigned)f2bf(v.y) << 16);
    }
  }
}

// ---------------------------------------------------------------- stage 2: GEMM + GELU + residual
// 128(px) x 128(ch) tile, BK=64, 16 K-steps, 4 waves (2x2), wave tile
// 64px x 64ch, 2 MFMA k-halves per acc (32 MFMA/wave/step). Double-buffered
// 64KB LDS, counted vmcnt(8), raw barriers, setprio. Full 3-bit XOR swizzle
// for 128B rows: LDS chunk16 c' = c ^ (row&7), via pre-swizzled global source
// (chunk (l&7)^(l>>3) per staging lane) + matching ds_read offsets — every
// frag-read instr covers all 8 bank-sets x 8 lanes (optimal).
#define GLOAD16(gsrc, ldst)                                                     \
  __builtin_amdgcn_global_load_lds(                                             \
      (const __attribute__((address_space(1))) unsigned int*)(gsrc),            \
      (__attribute__((address_space(3))) unsigned int*)(ldst), 16, 0, 0)

__global__ __launch_bounds__(256) void gemm_gelu_kernel(
    const unsigned short* __restrict__ A,   // d bf16 [NPIX][1024]
    const unsigned short* __restrict__ Bw,  // conv_w bf16 [o][c]
    const float* __restrict__ bias,
    const float* __restrict__ x,
    float* __restrict__ out) {
  __shared__ unsigned short lA[2 * 8192];   // 32 KB: [buf][128 rows][64 k]
  __shared__ unsigned short lB[2 * 8192];   // 32 KB

  // XCD swizzle: 1568 = 8 XCD * 196; n-inner so the 8 n-tiles sharing an
  // A-panel run consecutively on the same XCD (W 2MB is L2-resident).
  int bid = blockIdx.x;
  int j = (bid & 7) * 196 + (bid >> 3);
  int mt = j >> 3, nt = j & 7;          // 196 px-tiles x 8 ch-tiles
  int p0 = mt * 128, n0 = nt * 128;

  int tid = threadIdx.x;
  int l = tid & 63, wid = tid >> 6;
  int wr = wid >> 1, wc = wid & 1;      // wave tile: px p0+wr*64, ch n0+wc*64
  int lr = l & 15, lg = l >> 4;

  f32x4 acc[4][4];   // [ch frag][px frag]
#pragma unroll
  for (int i = 0; i < 4; ++i)
#pragma unroll
    for (int jj = 0; jj < 4; ++jj) acc[i][jj] = f32x4{0.f, 0.f, 0.f, 0.f};

  // staging: wave wid stages rows [wid*32, wid*32+32), 4 calls of 1KB each.
  // lane l in call jc: row = wid*32 + jc*8 + (l>>3), chunk16 c = l&7,
  // source chunk = c ^ (row&7) = (l&7) ^ (l>>3)  (jc*8, wid*32 are 0 mod 8).
  int srow = wid * 32 + (l >> 3);
  int scg  = (l & 7) ^ (l >> 3);
  const unsigned short* agA = A  + (size_t)(p0 + srow) * CCH + scg * 8;
  const unsigned short* agB = Bw + (size_t)(n0 + srow) * CCH + scg * 8;
  unsigned short* laW = lA + wid * 2048;   // wave quarter (4KB), +jc*512 per call
  unsigned short* lbW = lB + wid * 2048;

  // frag reads: row = (wr|wc)*64 + m*16 + lr (row&7 == lr&7); k-half h:
  // logical chunk = h*4+lg, physical = (h*4+lg) ^ (lr&7).
  int kx0 = ((0 * 4 + lg) ^ (lr & 7)) << 3;   // shorts
  int kx1 = ((1 * 4 + lg) ^ (lr & 7)) << 3;
  const unsigned short* lAf0 = lA + (wr * 64 + lr) * 64;
  const unsigned short* lBf0 = lB + (wc * 64 + lr) * 64;

#define STAGE(buf, kt)                                                          \
  do {                                                                          \
    _Pragma("unroll") for (int jc = 0; jc < 4; ++jc)                            \
      GLOAD16(agA + ((size_t)jc * 8) * CCH + (kt) * 64, laW + (buf) * 8192 + jc * 512); \
    _Pragma("unroll") for (int jc = 0; jc < 4; ++jc)                            \
      GLOAD16(agB + ((size_t)jc * 8) * CCH + (kt) * 64, lbW + (buf) * 8192 + jc * 512); \
  } while (0)

  STAGE(0, 0);
  __builtin_amdgcn_sched_barrier(0);
  asm volatile("s_waitcnt vmcnt(0)" ::: "memory");
  __builtin_amdgcn_s_barrier();
  __builtin_amdgcn_sched_barrier(0);

  int cur = 0;
#pragma unroll 2
  for (int kk = 0; kk < 16; ++kk) {
    STAGE(cur ^ 1, (kk + 1) & 15);      // prefetch next K-tile (wrap: dead re-stage)
    __builtin_amdgcn_sched_barrier(0);
    asm volatile("s_waitcnt vmcnt(8)" ::: "memory");   // current tile's 8 landed
    __builtin_amdgcn_s_barrier();
    __builtin_amdgcn_sched_barrier(0);

    short8 af[4][2], bf[4][2];
    const unsigned short* lAf = lAf0 + cur * 8192;
    const unsigned short* lBf = lBf0 + cur * 8192;
#pragma unroll
    for (int m = 0; m < 4; ++m) {
      af[m][0] = *(const short8*)(lAf + m * 1024 + kx0);
      af[m][1] = *(const short8*)(lAf + m * 1024 + kx1);
    }
#pragma unroll
    for (int n = 0; n < 4; ++n) {
      bf[n][0] = *(const short8*)(lBf + n * 1024 + kx0);
      bf[n][1] = *(const short8*)(lBf + n * 1024 + kx1);
    }
    __builtin_amdgcn_s_setprio(1);
#pragma unroll
    for (int i = 0; i < 4; ++i)         // ch frags (W rows as M)
#pragma unroll
      for (int jj = 0; jj < 4; ++jj) {  // px frags (d rows as N)
        acc[i][jj] = __builtin_amdgcn_mfma_f32_16x16x32_bf16(bf[i][0], af[jj][0], acc[i][jj], 0, 0, 0);
        acc[i][jj] = __builtin_amdgcn_mfma_f32_16x16x32_bf16(bf[i][1], af[jj][1], acc[i][jj], 0, 0, 0);
      }
    __builtin_amdgcn_s_setprio(0);
    __builtin_amdgcn_sched_barrier(0);
    __builtin_amdgcn_s_barrier();       // reads done -> cur re-stageable
    __builtin_amdgcn_sched_barrier(0);
    cur ^= 1;
  }
#undef STAGE
  asm volatile("s_waitcnt vmcnt(0)" ::: "memory");     // drain wrap-stage leftovers

  // epilogue: D row = (lane>>4)*4 + reg (=channel), col = lane&15 (=pixel)
  // jj innermost: 4 adjacent 64B stores per (i,r).
  int btb[4], hwb[4];
#pragma unroll
  for (int jj = 0; jj < 4; ++jj) {
    int px = p0 + wr * 64 + jj * 16 + lr;
    btb[jj] = px / HWN;
    hwb[jj] = px - btb[jj] * HWN;
  }
#pragma unroll
  for (int i = 0; i < 4; ++i) {
    int ch = n0 + wc * 64 + i * 16 + lg * 4;
#pragma unroll
    for (int r = 0; r < 4; ++r) {
      float bcol = bias[ch + r];
#pragma unroll
      for (int jj = 0; jj < 4; ++jj) {
        size_t idx = (size_t)btb[jj] * BTSTR + (size_t)(ch + r) * HWN + hwb[jj];
        float v = acc[i][jj][r] + bcol;
        float ge = 0.5f * v * (1.0f + erff(v * 0.70710678118654752f));
        out[idx] = x[idx] + ge;
      }
    }
  }
}

// ---------------------------------------------------------------- launcher
extern "C" void kernel_launch(void* const* d_in, const int* in_sizes, int n_in,
                              void* d_out, int out_size, void* d_ws, size_t ws_size,
                              hipStream_t stream) {
  const float* x      = (const float*)d_in[0];
  const float* wfilt  = (const float*)d_in[1];
  const float* conv_w = (const float*)d_in[2];
  const float* conv_b = (const float*)d_in[3];
  char* ws = (char*)d_ws;
  unsigned short* dmat = (unsigned short*)(ws + WS_D);
  unsigned short* bw   = (unsigned short*)(ws + WS_BW);
  float* out           = (float*)d_out;

  wcast_kernel<<<1024, 256, 0, stream>>>(conv_w, bw);
  fft_filter_kernel<<<3136, 256, 0, stream>>>(x, wfilt, dmat);
  gemm_gelu_kernel<<<1568, 256, 0, stream>>>(dmat, bw, conv_b, x, out);
}

// Round 11
// 215.590 us; speedup vs baseline: 1.1920x; 1.1920x over previous
//
#include <hip/hip_runtime.h>
#include <hip/hip_bf16.h>
#include <math.h>

typedef short short8 __attribute__((ext_vector_type(8)));
typedef float f32x4 __attribute__((ext_vector_type(4)));

// ---- problem dims (fixed by setup_inputs) ----
#define BTN   128            // b*t
#define HWN   196            // 14*14
#define CCH   1024
#define NPIX  (BTN * HWN)    // 25088
#define BTSTR (CCH * HWN)    // 200704 floats per bt slab

// ---- workspace layout (bytes) ----
#define WS_D  0                      // d matrix bf16 [NPIX][1024]
#define WS_BW 51380224               // conv_w bf16 [1024][1024]

// ---- complex helpers ----
__device__ __forceinline__ float2 cadd(float2 a, float2 b) { return make_float2(a.x + b.x, a.y + b.y); }
__device__ __forceinline__ float2 csub(float2 a, float2 b) { return make_float2(a.x - b.x, a.y - b.y); }
__device__ __forceinline__ float2 cmulf(float2 a, float2 b) {
  return make_float2(a.x * b.x - a.y * b.y, a.x * b.y + a.y * b.x);
}
__device__ __forceinline__ float2 cmulc(float2 a, float2 b) {   // a * conj(b)
  return make_float2(a.x * b.x + a.y * b.y, a.y * b.x - a.x * b.y);
}
__device__ __forceinline__ float2 csqr(float2 a) {
  return make_float2(a.x * a.x - a.y * a.y, 2.f * a.x * a.y);
}
__device__ __forceinline__ float2 cneg(float2 a) { return make_float2(-a.x, -a.y); }
__device__ __forceinline__ unsigned short f2bf(float f) {   // RNE fp32->bf16
  unsigned u = __float_as_uint(f);
  unsigned r = (u + 0x7fffu + ((u >> 16) & 1u)) >> 16;
  return (unsigned short)r;
}

// ---------------------------------------------------------------- W -> bf16
__global__ void wcast_kernel(const float* __restrict__ w, unsigned short* __restrict__ o) {
  int i = (blockIdx.x * 256 + threadIdx.x) * 4;
  float4 v = *(const float4*)(w + i);
  uint2 u;
  u.x = (unsigned)f2bf(v.x) | ((unsigned)f2bf(v.y) << 16);
  u.y = (unsigned)f2bf(v.z) | ((unsigned)f2bf(v.w) << 16);
  *(uint2*)(o + i) = u;
}

// ---------------------------------------------------------------- stage 1: FFT filter
// R3/R5 version verbatim (proven ~78us).
#define TS 1028   // tile row stride in floats: 1028 % 32 == 4 -> 2-way on stage writes

__global__ __launch_bounds__(256) void fft_filter_kernel(
    const float* __restrict__ x, const float* __restrict__ wfilt,
    unsigned short* __restrict__ dmat) {
  __shared__ float tile[8 * TS];
  __shared__ float2 tw10s[257];
  int tid = threadIdx.x;
  int l = tid & 63, w = tid >> 6;

  for (int i = tid; i < 257; i += 256) {
    float s, c;
    __sincosf(-6.283185307179586f * (float)i / 1024.0f, &s, &c);
    tw10s[i] = make_float2(c, s);
  }

  int blk = (blockIdx.x & 7) * 392 + (blockIdx.x >> 3);   // 3136 = 8 * 392
  int p_base = blk * 8;

  {
    int g = tid & 1, chb = tid >> 1;
    int p = p_base + 4 * g;
    int bt = p / HWN, hw = p - bt * HWN;          // hw%4==0, group stays in row
    const float* src = x + (size_t)bt * BTSTR + hw;
    float* rowb = tile + (4 * g) * TS;
#pragma unroll
    for (int it = 0; it < 8; ++it) {
      int c = chb + 128 * it;
      float4 v = *(const float4*)(src + (size_t)c * HWN);
      float* b = rowb + c;
      b[0 * TS] = v.x; b[1 * TS] = v.y; b[2 * TS] = v.z; b[3 * TS] = v.w;
    }
  }
  __syncthreads();

  const float H = 0.70710678118654752f;
  float2 Wl;
  { float s, c; __sincosf(-6.283185307179586f * (float)l / 512.0f, &s, &c); Wl = make_float2(c, s); }
  float2 W2l = csqr(Wl), W4l = csqr(W2l);
  float2 W2li = make_float2(W2l.y, -W2l.x);
  float2 T01 = cmulf(Wl, make_float2(H, -H));
  float2 T02 = make_float2(Wl.y, -Wl.x);
  float2 T03 = cmulf(Wl, make_float2(-H, -H));
  float2 t3 = csqr(W4l); if (l & 32) t3 = cneg(t3);
  float2 t4 = csqr(t3);  if (l & 16) t4 = cneg(t4);
  float2 t5 = csqr(t4);  if (l & 8)  t5 = cneg(t5);
  float2 t6 = csqr(t5);  if (l & 4)  t6 = cneg(t6);
  float2 t7 = csqr(t6);  if (l & 2)  t7 = cneg(t7);

#pragma unroll 1
  for (int pp = 0; pp < 2; ++pp) {
    int px = w * 2 + pp;
    int p = p_base + px;
    int bt = p / HWN, hw = p - bt * HWN;
    float2* zrow = (float2*)(tile + px * TS);

    float2 zr[8];
#pragma unroll
    for (int r = 0; r < 8; ++r) zr[r] = zrow[l + 64 * r];

    {
      float2 T0[4] = {Wl, T01, T02, T03};
#pragma unroll
      for (int r = 0; r < 4; ++r) {
        float2 a = zr[r], b = zr[r + 4];
        zr[r] = cadd(a, b);
        zr[r + 4] = cmulf(csub(a, b), T0[r]);
      }
    }
#pragma unroll
    for (int h = 0; h < 2; ++h) {
      int b0 = h * 4;
      float2 a = zr[b0], b = zr[b0 + 2];
      zr[b0] = cadd(a, b); zr[b0 + 2] = cmulf(csub(a, b), W2l);
      a = zr[b0 + 1]; b = zr[b0 + 3];
      zr[b0 + 1] = cadd(a, b); zr[b0 + 3] = cmulf(csub(a, b), W2li);
    }
#pragma unroll
    for (int r = 0; r < 8; r += 2) {
      float2 a = zr[r], b = zr[r + 1];
      zr[r] = cadd(a, b); zr[r + 1] = cmulf(csub(a, b), W4l);
    }
    {
      float2 tws[6] = {t3, t4, t5, t6, t7, make_float2(1.f, 0.f)};
      int masks[6] = {32, 16, 8, 4, 2, 1};
#pragma unroll
      for (int s = 0; s < 6; ++s) {
        int m = masks[s];
        bool up = (l & m) != 0;
        float2 te = up ? tws[s] : make_float2(1.f, 0.f);
#pragma unroll
        for (int r = 0; r < 8; ++r) {
          float2 v = zr[r];
          float2 o = make_float2(__shfl_xor(v.x, m, 64), __shfl_xor(v.y, m, 64));
          float2 d = up ? csub(o, v) : cadd(v, o);
          zr[r] = cmulf(d, te);
        }
      }
    }

#pragma unroll
    for (int r = 0; r < 8; ++r) zrow[l + 64 * r] = zr[r];
    {
      float2* z = zrow;
      const float* wf = wfilt + (size_t)((bt & 7) * HWN + hw) * 1026;
      const float sc = 1.0f / 512.0f;
#pragma unroll
      for (int i = 0; i < 4; ++i) {
        int f = 64 * i + l;
        if (f == 0) {
          float2 z0 = z[0];
          float X0 = z0.x + z0.y, X512 = z0.x - z0.y;
          float Y0 = X0 * wf[0] * sc;
          float Y512 = X512 * wf[1024] * sc;
          z[0] = make_float2(0.5f * (Y0 + Y512), 0.5f * (Y0 - Y512));
          float2 z2 = z[1];
          float2 X256 = make_float2(z2.x, -z2.y);
          float2 Y = cmulf(X256, make_float2(wf[512], wf[513]));
          z[1] = make_float2(Y.x * sc, -Y.y * sc);
        } else {
          int g = 512 - f;
          int pf = (int)(__brev((unsigned)f) >> 23);
          int pg = (int)(__brev((unsigned)g) >> 23);
          float2 Zf = z[pf], Zg = z[pg];
          float2 A = make_float2(0.5f * (Zf.x + Zg.x), 0.5f * (Zf.y - Zg.y));
          float2 B = make_float2(0.5f * (Zf.y + Zg.y), -0.5f * (Zf.x - Zg.x));
          float2 Wf = tw10s[f];
          float2 WB = cmulf(Wf, B);
          float2 Xf = make_float2(A.x + WB.x, A.y + WB.y);
          float2 Xg = make_float2(A.x - WB.x, -(A.y - WB.y));
          float2 Yf = cmulf(Xf, make_float2(wf[2 * f], wf[2 * f + 1]));
          float2 Yg = cmulf(Xg, make_float2(wf[2 * g], wf[2 * g + 1]));
          Yf.x *= sc; Yf.y *= sc; Yg.x *= sc; Yg.y *= sc;
          float2 Ap = make_float2(0.5f * (Yf.x + Yg.x), 0.5f * (Yf.y - Yg.y));
          float2 T  = make_float2(0.5f * (Yf.x - Yg.x), 0.5f * (Yf.y + Yg.y));
          float2 Bp = cmulf(make_float2(Wf.x, -Wf.y), T);
          z[pf] = make_float2(Ap.x - Bp.y, Ap.y + Bp.x);
          z[pg] = make_float2(Ap.x + Bp.y, Bp.x - Ap.y);
        }
      }
    }
#pragma unroll
    for (int r = 0; r < 8; ++r) zr[r] = zrow[l + 64 * r];

    {
      float2 tws[6] = {make_float2(1.f, 0.f), t7, t6, t5, t4, t3};
      int masks[6] = {1, 2, 4, 8, 16, 32};
#pragma unroll
      for (int s = 0; s < 6; ++s) {
        int m = masks[s];
        bool up = (l & m) != 0;
        float2 te = up ? make_float2(tws[s].x, -tws[s].y) : make_float2(1.f, 0.f);
#pragma unroll
        for (int r = 0; r < 8; ++r) {
          float2 v = cmulf(zr[r], te);
          float2 o = make_float2(__shfl_xor(v.x, m, 64), __shfl_xor(v.y, m, 64));
          zr[r] = up ? csub(o, v) : cadd(v, o);
        }
      }
    }
#pragma unroll
    for (int r = 0; r < 8; r += 2) {
      float2 v = cmulc(zr[r + 1], W4l);
      float2 a = zr[r];
      zr[r] = cadd(a, v); zr[r + 1] = csub(a, v);
    }
#pragma unroll
    for (int h = 0; h < 2; ++h) {
      int b0 = h * 4;
      float2 v = cmulc(zr[b0 + 2], W2l);
      float2 a = zr[b0];
      zr[b0] = cadd(a, v); zr[b0 + 2] = csub(a, v);
      v = cmulc(zr[b0 + 3], W2li);
      a = zr[b0 + 1];
      zr[b0 + 1] = cadd(a, v); zr[b0 + 3] = csub(a, v);
    }
    {
      float2 T0[4] = {Wl, T01, T02, T03};
#pragma unroll
      for (int r = 0; r < 4; ++r) {
        float2 v = cmulc(zr[r + 4], T0[r]);
        float2 a = zr[r];
        zr[r] = cadd(a, v); zr[r + 4] = csub(a, v);
      }
    }

    unsigned* dst = (unsigned*)(dmat + (size_t)p * CCH);
#pragma unroll
    for (int r = 0; r < 8; ++r) {
      float2 v = zr[r];
      dst[l + 64 * r] = (unsigned)f2bf(v.x) | ((unsigned)f2bf(v.y) << 16);
    }
  }
}

// ---------------------------------------------------------------- stage 2: GEMM + GELU + residual
// 128(px) x 128(ch) tile, BK=32, 8 waves (2 px-groups x 4 ch-groups), wave
// tile 64px x 32ch -> acc[2][4] = 32 AGPR/wave (occupancy lever: arch+acc
// target <=85 regs -> 6 waves/SIMD -> 3 blocks/CU = 24 waves/CU).
// All R5-proven levers: 2-phase counted vmcnt(2), raw barriers, setprio,
// 2-way both-sides swizzle, XCD n-inner swizzle. LDS 32KB dbuf.
#define GLOAD16(gsrc, ldst)                                                     \
  __builtin_amdgcn_global_load_lds(                                             \
      (const __attribute__((address_space(1))) unsigned int*)(gsrc),            \
      (__attribute__((address_space(3))) unsigned int*)(ldst), 16, 0, 0)

__global__ __launch_bounds__(512) void gemm_gelu_kernel(
    const unsigned short* __restrict__ A,   // d bf16 [NPIX][1024]
    const unsigned short* __restrict__ Bw,  // conv_w bf16 [o][c]
    const float* __restrict__ bias,
    const float* __restrict__ x,
    float* __restrict__ out) {
  __shared__ unsigned short lA[2 * 4096];   // 16 KB: [buf][128 px rows][32 k]
  __shared__ unsigned short lB[2 * 4096];   // 16 KB: [buf][128 ch rows][32 k]

  // XCD swizzle: 1568 = 8 XCD * 196; n-inner so the 8 n-tiles sharing an
  // A-panel run consecutively on the same XCD (W 2MB is L2-resident).
  int bid = blockIdx.x;
  int j = (bid & 7) * 196 + (bid >> 3);
  int mt = j >> 3, nt = j & 7;          // 196 px-tiles x 8 ch-tiles
  int p0 = mt * 128, n0 = nt * 128;

  int tid = threadIdx.x;
  int l = tid & 63, wid = tid >> 6;
  int wr = wid >> 2, wc = wid & 3;      // wave tile: px p0+wr*64, ch n0+wc*32
  int lr = l & 15, lg = l >> 4;

  f32x4 acc[2][4];   // [ch frag][px frag] = 32 AGPR
#pragma unroll
  for (int i = 0; i < 2; ++i)
#pragma unroll
    for (int jj = 0; jj < 4; ++jj) acc[i][jj] = f32x4{0.f, 0.f, 0.f, 0.f};

  // staging: 512 thr, 1 GLOAD16 each for A and B. thread -> row = tid>>2,
  // chunk16 = tid&3, source-swizzled: LDS slot (row,c) holds global chunk
  // c ^ ((row>>1)&3), and (row>>1)&3 == (tid>>3)&3.
  int arow = tid >> 2;
  int acg = (tid & 3) ^ ((tid >> 3) & 3);
  const unsigned short* agA = A  + (size_t)(p0 + arow) * CCH + acg * 8;
  const unsigned short* agB = Bw + (size_t)(n0 + arow) * CCH + acg * 8;
  unsigned short* laW = lA + wid * 512;   // wave-uniform bases (lane*16B HW-added)
  unsigned short* lbW = lB + wid * 512;

  // frag-read k-offset: logical chunk lg at physical lg ^ ((row>>1)&3) =
  // lg ^ ((lr>>1)&3) (frag rows = 64|32-multiples + lr).
  int kx = ((lg ^ ((lr >> 1) & 3)) << 3);
  const unsigned short* lAf0 = lA + (wr * 64 + lr) * 32 + kx;
  const unsigned short* lBf0 = lB + (wc * 32 + lr) * 32 + kx;

#define STAGE(buf, kt)                                                          \
  do {                                                                          \
    GLOAD16(agA + (kt) * 32, laW + (buf) * 4096);                               \
    GLOAD16(agB + (kt) * 32, lbW + (buf) * 4096);                               \
  } while (0)

  STAGE(0, 0);
  __builtin_amdgcn_sched_barrier(0);
  asm volatile("s_waitcnt vmcnt(0)" ::: "memory");
  __builtin_amdgcn_s_barrier();
  __builtin_amdgcn_sched_barrier(0);

  int cur = 0;
#pragma unroll 2
  for (int kk = 0; kk < 32; ++kk) {
    STAGE(cur ^ 1, (kk + 1) & 31);      // prefetch next tile (wrap: dead re-stage)
    __builtin_amdgcn_sched_barrier(0);
    asm volatile("s_waitcnt vmcnt(2)" ::: "memory");   // current tile's 2 landed
    __builtin_amdgcn_s_barrier();
    __builtin_amdgcn_sched_barrier(0);

    short8 af[4], bf[2];
    const unsigned short* lAf = lAf0 + cur * 4096;
    const unsigned short* lBf = lBf0 + cur * 4096;
#pragma unroll
    for (int m = 0; m < 4; ++m) af[m] = *(const short8*)(lAf + m * 512);
#pragma unroll
    for (int n = 0; n < 2; ++n) bf[n] = *(const short8*)(lBf + n * 512);
    __builtin_amdgcn_s_setprio(1);
#pragma unroll
    for (int i = 0; i < 2; ++i)         // ch frags (W rows as M)
#pragma unroll
      for (int jj = 0; jj < 4; ++jj)    // px frags (d rows as N)
        acc[i][jj] = __builtin_amdgcn_mfma_f32_16x16x32_bf16(bf[i], af[jj], acc[i][jj], 0, 0, 0);
    __builtin_amdgcn_s_setprio(0);
    __builtin_amdgcn_sched_barrier(0);
    __builtin_amdgcn_s_barrier();       // reads done -> cur re-stageable
    __builtin_amdgcn_sched_barrier(0);
    cur ^= 1;
  }
#undef STAGE
  asm volatile("s_waitcnt vmcnt(0)" ::: "memory");     // drain wrap-stage leftovers

  // epilogue: D row = (lane>>4)*4 + reg (=channel), col = lane&15 (=pixel)
  // jj innermost: 4 adjacent 64B stores per (i,r).
  int btb[4], hwb[4];
#pragma unroll
  for (int jj = 0; jj < 4; ++jj) {
    int px = p0 + wr * 64 + jj * 16 + lr;
    btb[jj] = px / HWN;
    hwb[jj] = px - btb[jj] * HWN;
  }
#pragma unroll
  for (int i = 0; i < 2; ++i) {
    int ch = n0 + wc * 32 + i * 16 + lg * 4;
#pragma unroll
    for (int r = 0; r < 4; ++r) {
      float bcol = bias[ch + r];
#pragma unroll
      for (int jj = 0; jj < 4; ++jj) {
        size_t idx = (size_t)btb[jj] * BTSTR + (size_t)(ch + r) * HWN + hwb[jj];
        float v = acc[i][jj][r] + bcol;
        float ge = 0.5f * v * (1.0f + erff(v * 0.70710678118654752f));
        out[idx] = x[idx] + ge;
      }
    }
  }
}

// ---------------------------------------------------------------- launcher
extern "C" void kernel_launch(void* const* d_in, const int* in_sizes, int n_in,
                              void* d_out, int out_size, void* d_ws, size_t ws_size,
                              hipStream_t stream) {
  const float* x      = (const float*)d_in[0];
  const float* wfilt  = (const float*)d_in[1];
  const float* conv_w = (const float*)d_in[2];
  const float* conv_b = (const float*)d_in[3];
  char* ws = (char*)d_ws;
  unsigned short* dmat = (unsigned short*)(ws + WS_D);
  unsigned short* bw   = (unsigned short*)(ws + WS_BW);
  float* out           = (float*)d_out;

  wcast_kernel<<<1024, 256, 0, stream>>>(conv_w, bw);
  fft_filter_kernel<<<3136, 256, 0, stream>>>(x, wfilt, dmat);
  gemm_gelu_kernel<<<1568, 512, 0, stream>>>(dmat, bw, conv_b, x, out);
}

// Round 12
// 192.706 us; speedup vs baseline: 1.3335x; 1.1187x over previous
//
#include <hip/hip_runtime.h>
#include <hip/hip_bf16.h>
#include <math.h>

typedef short short8 __attribute__((ext_vector_type(8)));
typedef float f32x4 __attribute__((ext_vector_type(4)));

// ---- problem dims (fixed by setup_inputs) ----
#define BTN   128            // b*t
#define HWN   196            // 14*14
#define CCH   1024
#define NPIX  (BTN * HWN)    // 25088
#define BTSTR (CCH * HWN)    // 200704 floats per bt slab

// ---- workspace layout (bytes) ----
#define WS_D  0                      // d matrix bf16 [NPIX][1024]
#define WS_BW 51380224               // conv_w bf16 [1024][1024]

// ---- complex helpers ----
__device__ __forceinline__ float2 cadd(float2 a, float2 b) { return make_float2(a.x + b.x, a.y + b.y); }
__device__ __forceinline__ float2 csub(float2 a, float2 b) { return make_float2(a.x - b.x, a.y - b.y); }
__device__ __forceinline__ float2 cmulf(float2 a, float2 b) {
  return make_float2(a.x * b.x - a.y * b.y, a.x * b.y + a.y * b.x);
}
__device__ __forceinline__ float2 cmulc(float2 a, float2 b) {   // a * conj(b)
  return make_float2(a.x * b.x + a.y * b.y, a.y * b.x - a.x * b.y);
}
__device__ __forceinline__ float2 csqr(float2 a) {
  return make_float2(a.x * a.x - a.y * a.y, 2.f * a.x * a.y);
}
__device__ __forceinline__ float2 cneg(float2 a) { return make_float2(-a.x, -a.y); }
__device__ __forceinline__ unsigned short f2bf(float f) {   // RNE fp32->bf16
  unsigned u = __float_as_uint(f);
  unsigned r = (u + 0x7fffu + ((u >> 16) & 1u)) >> 16;
  return (unsigned short)r;
}

// ---------------------------------------------------------------- W -> bf16
__global__ void wcast_kernel(const float* __restrict__ w, unsigned short* __restrict__ o) {
  int i = (blockIdx.x * 256 + threadIdx.x) * 4;
  float4 v = *(const float4*)(w + i);
  uint2 u;
  u.x = (unsigned)f2bf(v.x) | ((unsigned)f2bf(v.y) << 16);
  u.y = (unsigned)f2bf(v.z) | ((unsigned)f2bf(v.w) << 16);
  *(uint2*)(o + i) = u;
}

// ---------------------------------------------------------------- stage 1: FFT filter
// R3/R5 version verbatim (proven ~78us).
#define TS 1028   // tile row stride in floats: 1028 % 32 == 4 -> 2-way on stage writes

__global__ __launch_bounds__(256) void fft_filter_kernel(
    const float* __restrict__ x, const float* __restrict__ wfilt,
    unsigned short* __restrict__ dmat) {
  __shared__ float tile[8 * TS];
  __shared__ float2 tw10s[257];
  int tid = threadIdx.x;
  int l = tid & 63, w = tid >> 6;

  for (int i = tid; i < 257; i += 256) {
    float s, c;
    __sincosf(-6.283185307179586f * (float)i / 1024.0f, &s, &c);
    tw10s[i] = make_float2(c, s);
  }

  int blk = (blockIdx.x & 7) * 392 + (blockIdx.x >> 3);   // 3136 = 8 * 392
  int p_base = blk * 8;

  {
    int g = tid & 1, chb = tid >> 1;
    int p = p_base + 4 * g;
    int bt = p / HWN, hw = p - bt * HWN;          // hw%4==0, group stays in row
    const float* src = x + (size_t)bt * BTSTR + hw;
    float* rowb = tile + (4 * g) * TS;
#pragma unroll
    for (int it = 0; it < 8; ++it) {
      int c = chb + 128 * it;
      float4 v = *(const float4*)(src + (size_t)c * HWN);
      float* b = rowb + c;
      b[0 * TS] = v.x; b[1 * TS] = v.y; b[2 * TS] = v.z; b[3 * TS] = v.w;
    }
  }
  __syncthreads();

  const float H = 0.70710678118654752f;
  float2 Wl;
  { float s, c; __sincosf(-6.283185307179586f * (float)l / 512.0f, &s, &c); Wl = make_float2(c, s); }
  float2 W2l = csqr(Wl), W4l = csqr(W2l);
  float2 W2li = make_float2(W2l.y, -W2l.x);
  float2 T01 = cmulf(Wl, make_float2(H, -H));
  float2 T02 = make_float2(Wl.y, -Wl.x);
  float2 T03 = cmulf(Wl, make_float2(-H, -H));
  float2 t3 = csqr(W4l); if (l & 32) t3 = cneg(t3);
  float2 t4 = csqr(t3);  if (l & 16) t4 = cneg(t4);
  float2 t5 = csqr(t4);  if (l & 8)  t5 = cneg(t5);
  float2 t6 = csqr(t5);  if (l & 4)  t6 = cneg(t6);
  float2 t7 = csqr(t6);  if (l & 2)  t7 = cneg(t7);

#pragma unroll 1
  for (int pp = 0; pp < 2; ++pp) {
    int px = w * 2 + pp;
    int p = p_base + px;
    int bt = p / HWN, hw = p - bt * HWN;
    float2* zrow = (float2*)(tile + px * TS);

    float2 zr[8];
#pragma unroll
    for (int r = 0; r < 8; ++r) zr[r] = zrow[l + 64 * r];

    {
      float2 T0[4] = {Wl, T01, T02, T03};
#pragma unroll
      for (int r = 0; r < 4; ++r) {
        float2 a = zr[r], b = zr[r + 4];
        zr[r] = cadd(a, b);
        zr[r + 4] = cmulf(csub(a, b), T0[r]);
      }
    }
#pragma unroll
    for (int h = 0; h < 2; ++h) {
      int b0 = h * 4;
      float2 a = zr[b0], b = zr[b0 + 2];
      zr[b0] = cadd(a, b); zr[b0 + 2] = cmulf(csub(a, b), W2l);
      a = zr[b0 + 1]; b = zr[b0 + 3];
      zr[b0 + 1] = cadd(a, b); zr[b0 + 3] = cmulf(csub(a, b), W2li);
    }
#pragma unroll
    for (int r = 0; r < 8; r += 2) {
      float2 a = zr[r], b = zr[r + 1];
      zr[r] = cadd(a, b); zr[r + 1] = cmulf(csub(a, b), W4l);
    }
    {
      float2 tws[6] = {t3, t4, t5, t6, t7, make_float2(1.f, 0.f)};
      int masks[6] = {32, 16, 8, 4, 2, 1};
#pragma unroll
      for (int s = 0; s < 6; ++s) {
        int m = masks[s];
        bool up = (l & m) != 0;
        float2 te = up ? tws[s] : make_float2(1.f, 0.f);
#pragma unroll
        for (int r = 0; r < 8; ++r) {
          float2 v = zr[r];
          float2 o = make_float2(__shfl_xor(v.x, m, 64), __shfl_xor(v.y, m, 64));
          float2 d = up ? csub(o, v) : cadd(v, o);
          zr[r] = cmulf(d, te);
        }
      }
    }

#pragma unroll
    for (int r = 0; r < 8; ++r) zrow[l + 64 * r] = zr[r];
    {
      float2* z = zrow;
      const float* wf = wfilt + (size_t)((bt & 7) * HWN + hw) * 1026;
      const float sc = 1.0f / 512.0f;
#pragma unroll
      for (int i = 0; i < 4; ++i) {
        int f = 64 * i + l;
        if (f == 0) {
          float2 z0 = z[0];
          float X0 = z0.x + z0.y, X512 = z0.x - z0.y;
          float Y0 = X0 * wf[0] * sc;
          float Y512 = X512 * wf[1024] * sc;
          z[0] = make_float2(0.5f * (Y0 + Y512), 0.5f * (Y0 - Y512));
          float2 z2 = z[1];
          float2 X256 = make_float2(z2.x, -z2.y);
          float2 Y = cmulf(X256, make_float2(wf[512], wf[513]));
          z[1] = make_float2(Y.x * sc, -Y.y * sc);
        } else {
          int g = 512 - f;
          int pf = (int)(__brev((unsigned)f) >> 23);
          int pg = (int)(__brev((unsigned)g) >> 23);
          float2 Zf = z[pf], Zg = z[pg];
          float2 A = make_float2(0.5f * (Zf.x + Zg.x), 0.5f * (Zf.y - Zg.y));
          float2 B = make_float2(0.5f * (Zf.y + Zg.y), -0.5f * (Zf.x - Zg.x));
          float2 Wf = tw10s[f];
          float2 WB = cmulf(Wf, B);
          float2 Xf = make_float2(A.x + WB.x, A.y + WB.y);
          float2 Xg = make_float2(A.x - WB.x, -(A.y - WB.y));
          float2 Yf = cmulf(Xf, make_float2(wf[2 * f], wf[2 * f + 1]));
          float2 Yg = cmulf(Xg, make_float2(wf[2 * g], wf[2 * g + 1]));
          Yf.x *= sc; Yf.y *= sc; Yg.x *= sc; Yg.y *= sc;
          float2 Ap = make_float2(0.5f * (Yf.x + Yg.x), 0.5f * (Yf.y - Yg.y));
          float2 T  = make_float2(0.5f * (Yf.x - Yg.x), 0.5f * (Yf.y + Yg.y));
          float2 Bp = cmulf(make_float2(Wf.x, -Wf.y), T);
          z[pf] = make_float2(Ap.x - Bp.y, Ap.y + Bp.x);
          z[pg] = make_float2(Ap.x + Bp.y, Bp.x - Ap.y);
        }
      }
    }
#pragma unroll
    for (int r = 0; r < 8; ++r) zr[r] = zrow[l + 64 * r];

    {
      float2 tws[6] = {make_float2(1.f, 0.f), t7, t6, t5, t4, t3};
      int masks[6] = {1, 2, 4, 8, 16, 32};
#pragma unroll
      for (int s = 0; s < 6; ++s) {
        int m = masks[s];
        bool up = (l & m) != 0;
        float2 te = up ? make_float2(tws[s].x, -tws[s].y) : make_float2(1.f, 0.f);
#pragma unroll
        for (int r = 0; r < 8; ++r) {
          float2 v = cmulf(zr[r], te);
          float2 o = make_float2(__shfl_xor(v.x, m, 64), __shfl_xor(v.y, m, 64));
          zr[r] = up ? csub(o, v) : cadd(v, o);
        }
      }
    }
#pragma unroll
    for (int r = 0; r < 8; r += 2) {
      float2 v = cmulc(zr[r + 1], W4l);
      float2 a = zr[r];
      zr[r] = cadd(a, v); zr[r + 1] = csub(a, v);
    }
#pragma unroll
    for (int h = 0; h < 2; ++h) {
      int b0 = h * 4;
      float2 v = cmulc(zr[b0 + 2], W2l);
      float2 a = zr[b0];
      zr[b0] = cadd(a, v); zr[b0 + 2] = csub(a, v);
      v = cmulc(zr[b0 + 3], W2li);
      a = zr[b0 + 1];
      zr[b0 + 1] = cadd(a, v); zr[b0 + 3] = csub(a, v);
    }
    {
      float2 T0[4] = {Wl, T01, T02, T03};
#pragma unroll
      for (int r = 0; r < 4; ++r) {
        float2 v = cmulc(zr[r + 4], T0[r]);
        float2 a = zr[r];
        zr[r] = cadd(a, v); zr[r + 4] = csub(a, v);
      }
    }

    unsigned* dst = (unsigned*)(dmat + (size_t)p * CCH);
#pragma unroll
    for (int r = 0; r < 8; ++r) {
      float2 v = zr[r];
      dst[l + 64 * r] = (unsigned)f2bf(v.x) | ((unsigned)f2bf(v.y) << 16);
    }
  }
}

// ---------------------------------------------------------------- stage 2: GEMM + GELU + residual
// R11 main loop verbatim (128x128, BK=32, 8 waves 64px x 32ch, acc[2][4],
// counted vmcnt(2), 2-way both-sides swizzle, 3 blocks/CU @ 47% occ).
// NEW: coalesced epilogue — per-wave LDS transpose ([8][68] f32 slices), then
// float4 loads/stores over 64 consecutive pixels (4 ch x 256B windows per
// instr; 4x fewer L2 transactions, dwordx4 both ways).
#define GLOAD16(gsrc, ldst)                                                     \
  __builtin_amdgcn_global_load_lds(                                             \
      (const __attribute__((address_space(1))) unsigned int*)(gsrc),            \
      (__attribute__((address_space(3))) unsigned int*)(ldst), 16, 0, 0)

__global__ __launch_bounds__(512) void gemm_gelu_kernel(
    const unsigned short* __restrict__ A,   // d bf16 [NPIX][1024]
    const unsigned short* __restrict__ Bw,  // conv_w bf16 [o][c]
    const float* __restrict__ bias,
    const float* __restrict__ x,
    float* __restrict__ out) {
  __shared__ unsigned short SH[16384];      // 32 KB: lA [0,8192), lB [8192,16384)
  unsigned short* lA = SH;
  unsigned short* lB = SH + 8192;

  // XCD swizzle: 1568 = 8 XCD * 196; n-inner so the 8 n-tiles sharing an
  // A-panel run consecutively on the same XCD (W 2MB is L2-resident).
  int bid = blockIdx.x;
  int j = (bid & 7) * 196 + (bid >> 3);
  int mt = j >> 3, nt = j & 7;          // 196 px-tiles x 8 ch-tiles
  int p0 = mt * 128, n0 = nt * 128;

  int tid = threadIdx.x;
  int l = tid & 63, wid = tid >> 6;
  int wr = wid >> 2, wc = wid & 3;      // wave tile: px p0+wr*64, ch n0+wc*32
  int lr = l & 15, lg = l >> 4;

  f32x4 acc[2][4];   // [ch frag][px frag] = 32 AGPR
#pragma unroll
  for (int i = 0; i < 2; ++i)
#pragma unroll
    for (int jj = 0; jj < 4; ++jj) acc[i][jj] = f32x4{0.f, 0.f, 0.f, 0.f};

  // staging: 512 thr, 1 GLOAD16 each for A and B. thread -> row = tid>>2,
  // chunk16 = tid&3, source-swizzled: LDS slot (row,c) holds global chunk
  // c ^ ((row>>1)&3), and (row>>1)&3 == (tid>>3)&3.
  int arow = tid >> 2;
  int acg = (tid & 3) ^ ((tid >> 3) & 3);
  const unsigned short* agA = A  + (size_t)(p0 + arow) * CCH + acg * 8;
  const unsigned short* agB = Bw + (size_t)(n0 + arow) * CCH + acg * 8;
  unsigned short* laW = lA + wid * 512;   // wave-uniform bases (lane*16B HW-added)
  unsigned short* lbW = lB + wid * 512;

  // frag-read k-offset: logical chunk lg at physical lg ^ ((lr>>1)&3).
  int kx = ((lg ^ ((lr >> 1) & 3)) << 3);
  const unsigned short* lAf0 = lA + (wr * 64 + lr) * 32 + kx;
  const unsigned short* lBf0 = lB + (wc * 32 + lr) * 32 + kx;

#define STAGE(buf, kt)                                                          \
  do {                                                                          \
    GLOAD16(agA + (kt) * 32, laW + (buf) * 4096);                               \
    GLOAD16(agB + (kt) * 32, lbW + (buf) * 4096);                               \
  } while (0)

  STAGE(0, 0);
  __builtin_amdgcn_sched_barrier(0);
  asm volatile("s_waitcnt vmcnt(0)" ::: "memory");
  __builtin_amdgcn_s_barrier();
  __builtin_amdgcn_sched_barrier(0);

  int cur = 0;
#pragma unroll 2
  for (int kk = 0; kk < 32; ++kk) {
    STAGE(cur ^ 1, (kk + 1) & 31);      // prefetch next tile (wrap: dead re-stage)
    __builtin_amdgcn_sched_barrier(0);
    asm volatile("s_waitcnt vmcnt(2)" ::: "memory");   // current tile's 2 landed
    __builtin_amdgcn_s_barrier();
    __builtin_amdgcn_sched_barrier(0);

    short8 af[4], bf[2];
    const unsigned short* lAf = lAf0 + cur * 4096;
    const unsigned short* lBf = lBf0 + cur * 4096;
#pragma unroll
    for (int m = 0; m < 4; ++m) af[m] = *(const short8*)(lAf + m * 512);
#pragma unroll
    for (int n = 0; n < 2; ++n) bf[n] = *(const short8*)(lBf + n * 512);
    __builtin_amdgcn_s_setprio(1);
#pragma unroll
    for (int i = 0; i < 2; ++i)         // ch frags (W rows as M)
#pragma unroll
      for (int jj = 0; jj < 4; ++jj)    // px frags (d rows as N)
        acc[i][jj] = __builtin_amdgcn_mfma_f32_16x16x32_bf16(bf[i], af[jj], acc[i][jj], 0, 0, 0);
    __builtin_amdgcn_s_setprio(0);
    __builtin_amdgcn_sched_barrier(0);
    __builtin_amdgcn_s_barrier();       // reads done -> cur re-stageable
    __builtin_amdgcn_sched_barrier(0);
    cur ^= 1;
  }
#undef STAGE
  asm volatile("s_waitcnt vmcnt(0)" ::: "memory");     // drain wrap-stage leftovers
  __syncthreads();   // ALL waves' dead wrap-stage LDS writes landed -> LDS reusable

  // ---- coalesced epilogue via per-wave LDS transpose ----
  // wave slice: [8 ch][68 px] f32 = 2176B at float offset wid*544 (all 8 waves
  // fit in SH's 32KB). 4 passes over (i, rr): write 8 ch x 64 px, fence, then
  // 2 vector read+gelu+store rounds (each: 4 ch x 16 float4 = 64 contig px).
  float* tp = (float*)SH + wid * 544;
  int pxb = p0 + wr * 64 + (l & 15) * 4;          // 4-px group (4|196: no row cross)
  int btE = pxb / HWN, hwE = pxb - btE * HWN;
  size_t ebase = (size_t)btE * BTSTR + hwE;       // + ch*HWN per channel

#pragma unroll
  for (int i = 0; i < 2; ++i) {
#pragma unroll
    for (int rr = 0; rr < 2; ++rr) {
      // write phase: lanes (lr, lg); ch_local = lg*2+s, px = jj*16+lr
#pragma unroll
      for (int jj = 0; jj < 4; ++jj) {
#pragma unroll
        for (int s = 0; s < 2; ++s)
          tp[(lg * 2 + s) * 68 + jj * 16 + lr] = acc[i][jj][2 * rr + s];
      }
      asm volatile("s_waitcnt lgkmcnt(0)" ::: "memory");
      __builtin_amdgcn_sched_barrier(0);
      // read+store phase: lane -> ch_local cb+(l>>4), px4 = 4*(l&15)
#pragma unroll
      for (int cb = 0; cb < 8; cb += 4) {
        int ct = cb + (l >> 4);
        f32x4 v4 = *(const f32x4*)(tp + ct * 68 + (l & 15) * 4);
        int ch = n0 + wc * 32 + i * 16 + ((ct >> 1) << 2) + 2 * rr + (ct & 1);
        size_t idx = ebase + (size_t)ch * HWN;
        float4 xv = *(const float4*)(x + idx);
        float bc = bias[ch];
        float4 ov;
        {
          float v0 = v4[0] + bc, v1 = v4[1] + bc, v2 = v4[2] + bc, v3 = v4[3] + bc;
          ov.x = xv.x + 0.5f * v0 * (1.0f + erff(v0 * 0.70710678118654752f));
          ov.y = xv.y + 0.5f * v1 * (1.0f + erff(v1 * 0.70710678118654752f));
          ov.z = xv.z + 0.5f * v2 * (1.0f + erff(v2 * 0.70710678118654752f));
          ov.w = xv.w + 0.5f * v3 * (1.0f + erff(v3 * 0.70710678118654752f));
        }
        *(float4*)(out + idx) = ov;
      }
      __builtin_amdgcn_sched_barrier(0);   // keep passes ordered (LDS reuse)
    }
  }
}

// ---------------------------------------------------------------- launcher
extern "C" void kernel_launch(void* const* d_in, const int* in_sizes, int n_in,
                              void* d_out, int out_size, void* d_ws, size_t ws_size,
                              hipStream_t stream) {
  const float* x      = (const float*)d_in[0];
  const float* wfilt  = (const float*)d_in[1];
  const float* conv_w = (const float*)d_in[2];
  const float* conv_b = (const float*)d_in[3];
  char* ws = (char*)d_ws;
  unsigned short* dmat = (unsigned short*)(ws + WS_D);
  unsigned short* bw   = (unsigned short*)(ws + WS_BW);
  float* out           = (float*)d_out;

  wcast_kernel<<<1024, 256, 0, stream>>>(conv_w, bw);
  fft_filter_kernel<<<3136, 256, 0, stream>>>(x, wfilt, dmat);
  gemm_gelu_kernel<<<1568, 512, 0, stream>>>(dmat, bw, conv_b, x, out);
}

// Round 13
// 172.536 us; speedup vs baseline: 1.4894x; 1.1169x over previous
//
#include <hip/hip_runtime.h>
#include <hip/hip_bf16.h>
#include <math.h>

typedef short short8 __attribute__((ext_vector_type(8)));
typedef float f32x4 __attribute__((ext_vector_type(4)));

// ---- problem dims (fixed by setup_inputs) ----
#define BTN   128            // b*t
#define HWN   196            // 14*14
#define CCH   1024
#define NPIX  (BTN * HWN)    // 25088
#define BTSTR (CCH * HWN)    // 200704 floats per bt slab

// ---- workspace layout (bytes) ----
#define WS_D  0                      // d matrix bf16 [NPIX][1024]
#define WS_BW 51380224               // conv_w bf16 [1024][1024]

// ---- complex helpers ----
__device__ __forceinline__ float2 cadd(float2 a, float2 b) { return make_float2(a.x + b.x, a.y + b.y); }
__device__ __forceinline__ float2 csub(float2 a, float2 b) { return make_float2(a.x - b.x, a.y - b.y); }
__device__ __forceinline__ float2 cmulf(float2 a, float2 b) {
  return make_float2(a.x * b.x - a.y * b.y, a.x * b.y + a.y * b.x);
}
__device__ __forceinline__ float2 cmulc(float2 a, float2 b) {   // a * conj(b)
  return make_float2(a.x * b.x + a.y * b.y, a.y * b.x - a.x * b.y);
}
__device__ __forceinline__ float2 csqr(float2 a) {
  return make_float2(a.x * a.x - a.y * a.y, 2.f * a.x * a.y);
}
__device__ __forceinline__ float2 cneg(float2 a) { return make_float2(-a.x, -a.y); }
__device__ __forceinline__ unsigned short f2bf(float f) {   // RNE fp32->bf16
  unsigned u = __float_as_uint(f);
  unsigned r = (u + 0x7fffu + ((u >> 16) & 1u)) >> 16;
  return (unsigned short)r;
}

// ---------------------------------------------------------------- W -> bf16
__global__ void wcast_kernel(const float* __restrict__ w, unsigned short* __restrict__ o) {
  int i = (blockIdx.x * 256 + threadIdx.x) * 4;
  float4 v = *(const float4*)(w + i);
  uint2 u;
  u.x = (unsigned)f2bf(v.x) | ((unsigned)f2bf(v.y) << 16);
  u.y = (unsigned)f2bf(v.z) | ((unsigned)f2bf(v.w) << 16);
  *(uint2*)(o + i) = u;
}

// ---------------------------------------------------------------- stage 1: FFT filter
// R3/R5 structure; NEW: padded middle-phase LDS indexing (phys = i + (i>>3),
// row stride 1152 floats). Kills the 32-lanes-per-bank-pair pileup of the
// bitrev-scattered unpack (17.8M conflicts -> ~0): PIDX(pf) = 9*bitrev6(l)+c,
// 9R mod 16 bijective -> exactly 4 lane-slots/bank = wave64-b64 floor.
#define TS 1152   // padded row stride in floats (raw data uses [0,1024), padded middle [0,1150))

__global__ __launch_bounds__(256) void fft_filter_kernel(
    const float* __restrict__ x, const float* __restrict__ wfilt,
    unsigned short* __restrict__ dmat) {
  __shared__ float tile[8 * TS];
  __shared__ float2 tw10s[257];
  int tid = threadIdx.x;
  int l = tid & 63, w = tid >> 6;

  for (int i = tid; i < 257; i += 256) {
    float s, c;
    __sincosf(-6.283185307179586f * (float)i / 1024.0f, &s, &c);
    tw10s[i] = make_float2(c, s);
  }

  int blk = (blockIdx.x & 7) * 392 + (blockIdx.x >> 3);   // 3136 = 8 * 392
  int p_base = blk * 8;

  {
    int g = tid & 1, chb = tid >> 1;
    int p = p_base + 4 * g;
    int bt = p / HWN, hw = p - bt * HWN;          // hw%4==0, group stays in row
    const float* src = x + (size_t)bt * BTSTR + hw;
    float* rowb = tile + (4 * g) * TS;
#pragma unroll
    for (int it = 0; it < 8; ++it) {
      int c = chb + 128 * it;
      float4 v = *(const float4*)(src + (size_t)c * HWN);
      float* b = rowb + c;
      b[0 * TS] = v.x; b[1 * TS] = v.y; b[2 * TS] = v.z; b[3 * TS] = v.w;
    }
  }
  __syncthreads();

  const float H = 0.70710678118654752f;
  float2 Wl;
  { float s, c; __sincosf(-6.283185307179586f * (float)l / 512.0f, &s, &c); Wl = make_float2(c, s); }
  float2 W2l = csqr(Wl), W4l = csqr(W2l);
  float2 W2li = make_float2(W2l.y, -W2l.x);
  float2 T01 = cmulf(Wl, make_float2(H, -H));
  float2 T02 = make_float2(Wl.y, -Wl.x);
  float2 T03 = cmulf(Wl, make_float2(-H, -H));
  float2 t3 = csqr(W4l); if (l & 32) t3 = cneg(t3);
  float2 t4 = csqr(t3);  if (l & 16) t4 = cneg(t4);
  float2 t5 = csqr(t4);  if (l & 8)  t5 = cneg(t5);
  float2 t6 = csqr(t5);  if (l & 4)  t6 = cneg(t6);
  float2 t7 = csqr(t6);  if (l & 2)  t7 = cneg(t7);

#pragma unroll 1
  for (int pp = 0; pp < 2; ++pp) {
    int px = w * 2 + pp;
    int p = p_base + px;
    int bt = p / HWN, hw = p - bt * HWN;
    float2* zrow = (float2*)(tile + px * TS);

    float2 zr[8];
#pragma unroll
    for (int r = 0; r < 8; ++r) zr[r] = zrow[l + 64 * r];

    {
      float2 T0[4] = {Wl, T01, T02, T03};
#pragma unroll
      for (int r = 0; r < 4; ++r) {
        float2 a = zr[r], b = zr[r + 4];
        zr[r] = cadd(a, b);
        zr[r + 4] = cmulf(csub(a, b), T0[r]);
      }
    }
#pragma unroll
    for (int h = 0; h < 2; ++h) {
      int b0 = h * 4;
      float2 a = zr[b0], b = zr[b0 + 2];
      zr[b0] = cadd(a, b); zr[b0 + 2] = cmulf(csub(a, b), W2l);
      a = zr[b0 + 1]; b = zr[b0 + 3];
      zr[b0 + 1] = cadd(a, b); zr[b0 + 3] = cmulf(csub(a, b), W2li);
    }
#pragma unroll
    for (int r = 0; r < 8; r += 2) {
      float2 a = zr[r], b = zr[r + 1];
      zr[r] = cadd(a, b); zr[r + 1] = cmulf(csub(a, b), W4l);
    }
    {
      float2 tws[6] = {t3, t4, t5, t6, t7, make_float2(1.f, 0.f)};
      int masks[6] = {32, 16, 8, 4, 2, 1};
#pragma unroll
      for (int s = 0; s < 6; ++s) {
        int m = masks[s];
        bool up = (l & m) != 0;
        float2 te = up ? tws[s] : make_float2(1.f, 0.f);
#pragma unroll
        for (int r = 0; r < 8; ++r) {
          float2 v = zr[r];
          float2 o = make_float2(__shfl_xor(v.x, m, 64), __shfl_xor(v.y, m, 64));
          float2 d = up ? csub(o, v) : cadd(v, o);
          zr[r] = cmulf(d, te);
        }
      }
    }

    // ---- middle: spill to LDS PADDED (phys = i + (i>>3)), filter, reload ----
#pragma unroll
    for (int r = 0; r < 8; ++r) zrow[l + (l >> 3) + 72 * r] = zr[r];
    {
      float2* z = zrow;
      const float* wf = wfilt + (size_t)((bt & 7) * HWN + hw) * 1026;
      const float sc = 1.0f / 512.0f;
#pragma unroll
      for (int i = 0; i < 4; ++i) {
        int f = 64 * i + l;
        if (f == 0) {
          float2 z0 = z[0];
          float X0 = z0.x + z0.y, X512 = z0.x - z0.y;
          float Y0 = X0 * wf[0] * sc;
          float Y512 = X512 * wf[1024] * sc;
          z[0] = make_float2(0.5f * (Y0 + Y512), 0.5f * (Y0 - Y512));
          float2 z2 = z[1];
          float2 X256 = make_float2(z2.x, -z2.y);
          float2 Y = cmulf(X256, make_float2(wf[512], wf[513]));
          z[1] = make_float2(Y.x * sc, -Y.y * sc);
        } else {
          int g = 512 - f;
          int pf = (int)(__brev((unsigned)f) >> 23);
          int pg = (int)(__brev((unsigned)g) >> 23);
          int pf2 = pf + (pf >> 3), pg2 = pg + (pg >> 3);
          float2 Zf = z[pf2], Zg = z[pg2];
          float2 A = make_float2(0.5f * (Zf.x + Zg.x), 0.5f * (Zf.y - Zg.y));
          float2 B = make_float2(0.5f * (Zf.y + Zg.y), -0.5f * (Zf.x - Zg.x));
          float2 Wf = tw10s[f];
          float2 WB = cmulf(Wf, B);
          float2 Xf = make_float2(A.x + WB.x, A.y + WB.y);
          float2 Xg = make_float2(A.x - WB.x, -(A.y - WB.y));
          float2 Yf = cmulf(Xf, make_float2(wf[2 * f], wf[2 * f + 1]));
          float2 Yg = cmulf(Xg, make_float2(wf[2 * g], wf[2 * g + 1]));
          Yf.x *= sc; Yf.y *= sc; Yg.x *= sc; Yg.y *= sc;
          float2 Ap = make_float2(0.5f * (Yf.x + Yg.x), 0.5f * (Yf.y - Yg.y));
          float2 T  = make_float2(0.5f * (Yf.x - Yg.x), 0.5f * (Yf.y + Yg.y));
          float2 Bp = cmulf(make_float2(Wf.x, -Wf.y), T);
          z[pf2] = make_float2(Ap.x - Bp.y, Ap.y + Bp.x);
          z[pg2] = make_float2(Ap.x + Bp.y, Bp.x - Ap.y);
        }
      }
    }
#pragma unroll
    for (int r = 0; r < 8; ++r) zr[r] = zrow[l + (l >> 3) + 72 * r];

    {
      float2 tws[6] = {make_float2(1.f, 0.f), t7, t6, t5, t4, t3};
      int masks[6] = {1, 2, 4, 8, 16, 32};
#pragma unroll
      for (int s = 0; s < 6; ++s) {
        int m = masks[s];
        bool up = (l & m) != 0;
        float2 te = up ? make_float2(tws[s].x, -tws[s].y) : make_float2(1.f, 0.f);
#pragma unroll
        for (int r = 0; r < 8; ++r) {
          float2 v = cmulf(zr[r], te);
          float2 o = make_float2(__shfl_xor(v.x, m, 64), __shfl_xor(v.y, m, 64));
          zr[r] = up ? csub(o, v) : cadd(v, o);
        }
      }
    }
#pragma unroll
    for (int r = 0; r < 8; r += 2) {
      float2 v = cmulc(zr[r + 1], W4l);
      float2 a = zr[r];
      zr[r] = cadd(a, v); zr[r + 1] = csub(a, v);
    }
#pragma unroll
    for (int h = 0; h < 2; ++h) {
      int b0 = h * 4;
      float2 v = cmulc(zr[b0 + 2], W2l);
      float2 a = zr[b0];
      zr[b0] = cadd(a, v); zr[b0 + 2] = csub(a, v);
      v = cmulc(zr[b0 + 3], W2li);
      a = zr[b0 + 1];
      zr[b0 + 1] = cadd(a, v); zr[b0 + 3] = csub(a, v);
    }
    {
      float2 T0[4] = {Wl, T01, T02, T03};
#pragma unroll
      for (int r = 0; r < 4; ++r) {
        float2 v = cmulc(zr[r + 4], T0[r]);
        float2 a = zr[r];
        zr[r] = cadd(a, v); zr[r + 4] = csub(a, v);
      }
    }

    unsigned* dst = (unsigned*)(dmat + (size_t)p * CCH);
#pragma unroll
    for (int r = 0; r < 8; ++r) {
      float2 v = zr[r];
      dst[l + 64 * r] = (unsigned)f2bf(v.x) | ((unsigned)f2bf(v.y) << 16);
    }
  }
}

// ---------------------------------------------------------------- stage 2: GEMM + GELU + residual
// R12 verbatim (128x128, BK=32, 8 waves 64px x 32ch, acc[2][4], counted
// vmcnt(2), 2-way both-sides swizzle, 3 blocks/CU; coalesced LDS-transpose
// epilogue with float4 loads/stores over 64 consecutive pixels).
#define GLOAD16(gsrc, ldst)                                                     \
  __builtin_amdgcn_global_load_lds(                                             \
      (const __attribute__((address_space(1))) unsigned int*)(gsrc),            \
      (__attribute__((address_space(3))) unsigned int*)(ldst), 16, 0, 0)

__global__ __launch_bounds__(512) void gemm_gelu_kernel(
    const unsigned short* __restrict__ A,   // d bf16 [NPIX][1024]
    const unsigned short* __restrict__ Bw,  // conv_w bf16 [o][c]
    const float* __restrict__ bias,
    const float* __restrict__ x,
    float* __restrict__ out) {
  __shared__ unsigned short SH[16384];      // 32 KB: lA [0,8192), lB [8192,16384)
  unsigned short* lA = SH;
  unsigned short* lB = SH + 8192;

  int bid = blockIdx.x;
  int j = (bid & 7) * 196 + (bid >> 3);
  int mt = j >> 3, nt = j & 7;          // 196 px-tiles x 8 ch-tiles
  int p0 = mt * 128, n0 = nt * 128;

  int tid = threadIdx.x;
  int l = tid & 63, wid = tid >> 6;
  int wr = wid >> 2, wc = wid & 3;      // wave tile: px p0+wr*64, ch n0+wc*32
  int lr = l & 15, lg = l >> 4;

  f32x4 acc[2][4];   // [ch frag][px frag] = 32 AGPR
#pragma unroll
  for (int i = 0; i < 2; ++i)
#pragma unroll
    for (int jj = 0; jj < 4; ++jj) acc[i][jj] = f32x4{0.f, 0.f, 0.f, 0.f};

  int arow = tid >> 2;
  int acg = (tid & 3) ^ ((tid >> 3) & 3);
  const unsigned short* agA = A  + (size_t)(p0 + arow) * CCH + acg * 8;
  const unsigned short* agB = Bw + (size_t)(n0 + arow) * CCH + acg * 8;
  unsigned short* laW = lA + wid * 512;
  unsigned short* lbW = lB + wid * 512;

  int kx = ((lg ^ ((lr >> 1) & 3)) << 3);
  const unsigned short* lAf0 = lA + (wr * 64 + lr) * 32 + kx;
  const unsigned short* lBf0 = lB + (wc * 32 + lr) * 32 + kx;

#define STAGE(buf, kt)                                                          \
  do {                                                                          \
    GLOAD16(agA + (kt) * 32, laW + (buf) * 4096);                               \
    GLOAD16(agB + (kt) * 32, lbW + (buf) * 4096);                               \
  } while (0)

  STAGE(0, 0);
  __builtin_amdgcn_sched_barrier(0);
  asm volatile("s_waitcnt vmcnt(0)" ::: "memory");
  __builtin_amdgcn_s_barrier();
  __builtin_amdgcn_sched_barrier(0);

  int cur = 0;
#pragma unroll 2
  for (int kk = 0; kk < 32; ++kk) {
    STAGE(cur ^ 1, (kk + 1) & 31);      // prefetch next tile (wrap: dead re-stage)
    __builtin_amdgcn_sched_barrier(0);
    asm volatile("s_waitcnt vmcnt(2)" ::: "memory");   // current tile's 2 landed
    __builtin_amdgcn_s_barrier();
    __builtin_amdgcn_sched_barrier(0);

    short8 af[4], bf[2];
    const unsigned short* lAf = lAf0 + cur * 4096;
    const unsigned short* lBf = lBf0 + cur * 4096;
#pragma unroll
    for (int m = 0; m < 4; ++m) af[m] = *(const short8*)(lAf + m * 512);
#pragma unroll
    for (int n = 0; n < 2; ++n) bf[n] = *(const short8*)(lBf + n * 512);
    __builtin_amdgcn_s_setprio(1);
#pragma unroll
    for (int i = 0; i < 2; ++i)         // ch frags (W rows as M)
#pragma unroll
      for (int jj = 0; jj < 4; ++jj)    // px frags (d rows as N)
        acc[i][jj] = __builtin_amdgcn_mfma_f32_16x16x32_bf16(bf[i], af[jj], acc[i][jj], 0, 0, 0);
    __builtin_amdgcn_s_setprio(0);
    __builtin_amdgcn_sched_barrier(0);
    __builtin_amdgcn_s_barrier();       // reads done -> cur re-stageable
    __builtin_amdgcn_sched_barrier(0);
    cur ^= 1;
  }
#undef STAGE
  asm volatile("s_waitcnt vmcnt(0)" ::: "memory");     // drain wrap-stage leftovers
  __syncthreads();   // ALL waves' dead wrap-stage LDS writes landed -> LDS reusable

  // ---- coalesced epilogue via per-wave LDS transpose ----
  float* tp = (float*)SH + wid * 544;
  int pxb = p0 + wr * 64 + (l & 15) * 4;          // 4-px group (4|196: no row cross)
  int btE = pxb / HWN, hwE = pxb - btE * HWN;
  size_t ebase = (size_t)btE * BTSTR + hwE;       // + ch*HWN per channel

#pragma unroll
  for (int i = 0; i < 2; ++i) {
#pragma unroll
    for (int rr = 0; rr < 2; ++rr) {
#pragma unroll
      for (int jj = 0; jj < 4; ++jj) {
#pragma unroll
        for (int s = 0; s < 2; ++s)
          tp[(lg * 2 + s) * 68 + jj * 16 + lr] = acc[i][jj][2 * rr + s];
      }
      asm volatile("s_waitcnt lgkmcnt(0)" ::: "memory");
      __builtin_amdgcn_sched_barrier(0);
#pragma unroll
      for (int cb = 0; cb < 8; cb += 4) {
        int ct = cb + (l >> 4);
        f32x4 v4 = *(const f32x4*)(tp + ct * 68 + (l & 15) * 4);
        int ch = n0 + wc * 32 + i * 16 + ((ct >> 1) << 2) + 2 * rr + (ct & 1);
        size_t idx = ebase + (size_t)ch * HWN;
        float4 xv = *(const float4*)(x + idx);
        float bc = bias[ch];
        float4 ov;
        {
          float v0 = v4[0] + bc, v1 = v4[1] + bc, v2 = v4[2] + bc, v3 = v4[3] + bc;
          ov.x = xv.x + 0.5f * v0 * (1.0f + erff(v0 * 0.70710678118654752f));
          ov.y = xv.y + 0.5f * v1 * (1.0f + erff(v1 * 0.70710678118654752f));
          ov.z = xv.z + 0.5f * v2 * (1.0f + erff(v2 * 0.70710678118654752f));
          ov.w = xv.w + 0.5f * v3 * (1.0f + erff(v3 * 0.70710678118654752f));
        }
        *(float4*)(out + idx) = ov;
      }
      __builtin_amdgcn_sched_barrier(0);   // keep passes ordered (LDS reuse)
    }
  }
}

// ---------------------------------------------------------------- launcher
extern "C" void kernel_launch(void* const* d_in, const int* in_sizes, int n_in,
                              void* d_out, int out_size, void* d_ws, size_t ws_size,
                              hipStream_t stream) {
  const float* x      = (const float*)d_in[0];
  const float* wfilt  = (const float*)d_in[1];
  const float* conv_w = (const float*)d_in[2];
  const float* conv_b = (const float*)d_in[3];
  char* ws = (char*)d_ws;
  unsigned short* dmat = (unsigned short*)(ws + WS_D);
  unsigned short* bw   = (unsigned short*)(ws + WS_BW);
  float* out           = (float*)d_out;

  wcast_kernel<<<1024, 256, 0, stream>>>(conv_w, bw);
  fft_filter_kernel<<<3136, 256, 0, stream>>>(x, wfilt, dmat);
  gemm_gelu_kernel<<<1568, 512, 0, stream>>>(dmat, bw, conv_b, x, out);
}

// Round 14
// 168.217 us; speedup vs baseline: 1.5277x; 1.0257x over previous
//
#include <hip/hip_runtime.h>
#include <hip/hip_bf16.h>
#include <math.h>

typedef short short8 __attribute__((ext_vector_type(8)));
typedef float f32x4 __attribute__((ext_vector_type(4)));

// ---- problem dims (fixed by setup_inputs) ----
#define BTN   128            // b*t
#define HWN   196            // 14*14
#define CCH   1024
#define NPIX  (BTN * HWN)    // 25088
#define BTSTR (CCH * HWN)    // 200704 floats per bt slab

// ---- workspace layout (bytes) ----
#define WS_D  0                      // d matrix bf16 [NPIX][1024]
#define WS_BW 51380224               // conv_w bf16 [1024][1024]

// ---- complex helpers ----
__device__ __forceinline__ float2 cadd(float2 a, float2 b) { return make_float2(a.x + b.x, a.y + b.y); }
__device__ __forceinline__ float2 csub(float2 a, float2 b) { return make_float2(a.x - b.x, a.y - b.y); }
__device__ __forceinline__ float2 cmulf(float2 a, float2 b) {
  return make_float2(a.x * b.x - a.y * b.y, a.x * b.y + a.y * b.x);
}
__device__ __forceinline__ float2 cmulc(float2 a, float2 b) {   // a * conj(b)
  return make_float2(a.x * b.x + a.y * b.y, a.y * b.x - a.x * b.y);
}
__device__ __forceinline__ float2 csqr(float2 a) {
  return make_float2(a.x * a.x - a.y * a.y, 2.f * a.x * a.y);
}
__device__ __forceinline__ float2 cneg(float2 a) { return make_float2(-a.x, -a.y); }
__device__ __forceinline__ unsigned short f2bf(float f) {   // RNE fp32->bf16
  unsigned u = __float_as_uint(f);
  unsigned r = (u + 0x7fffu + ((u >> 16) & 1u)) >> 16;
  return (unsigned short)r;
}

// ---------------------------------------------------------------- W -> bf16
__global__ void wcast_kernel(const float* __restrict__ w, unsigned short* __restrict__ o) {
  int i = (blockIdx.x * 256 + threadIdx.x) * 4;
  float4 v = *(const float4*)(w + i);
  uint2 u;
  u.x = (unsigned)f2bf(v.x) | ((unsigned)f2bf(v.y) << 16);
  u.y = (unsigned)f2bf(v.z) | ((unsigned)f2bf(v.w) << 16);
  *(uint2*)(o + i) = u;
}

// ---------------------------------------------------------------- stage 1: FFT filter
// 256 thr, 8 px/block (proven staging). NEW vs R13:
// (a) phi16 padding: phys = i + (i>>4), row stride 1088 floats (544 float2).
//     Every 16-block of logical indices covers all 16 bank-pair residues
//     exactly once -> ANY permutation of 0..511 gives exactly 4 lanes per
//     bank-pair = b64 floor -> zero counted conflicts (spill/reload/middle).
// (b) both pixels of each wave interleaved in registers (z[2][8], R7-verified
//     math) -> 2x ILP on the 12 shfl stages and the middle section.
#define TS 1088   // padded row stride floats; raw staging uses [0,1024), phi16 max 542 float2 < 544

__global__ __launch_bounds__(256) void fft_filter_kernel(
    const float* __restrict__ x, const float* __restrict__ wfilt,
    unsigned short* __restrict__ dmat) {
  __shared__ float tile[8 * TS];
  __shared__ float2 tw10s[257];
  int tid = threadIdx.x;
  int l = tid & 63, w = tid >> 6;

  for (int i = tid; i < 257; i += 256) {
    float s, c;
    __sincosf(-6.283185307179586f * (float)i / 1024.0f, &s, &c);
    tw10s[i] = make_float2(c, s);
  }

  int blk = (blockIdx.x & 7) * 392 + (blockIdx.x >> 3);   // 3136 = 8 * 392
  int p_base = blk * 8;

  {
    int g = tid & 1, chb = tid >> 1;
    int p = p_base + 4 * g;
    int bt = p / HWN, hw = p - bt * HWN;          // hw%4==0, group stays in row
    const float* src = x + (size_t)bt * BTSTR + hw;
    float* rowb = tile + (4 * g) * TS;
#pragma unroll
    for (int it = 0; it < 8; ++it) {
      int c = chb + 128 * it;
      float4 v = *(const float4*)(src + (size_t)c * HWN);
      float* b = rowb + c;
      b[0 * TS] = v.x; b[1 * TS] = v.y; b[2 * TS] = v.z; b[3 * TS] = v.w;
    }
  }
  __syncthreads();

  const float H = 0.70710678118654752f;
  float2 Wl;
  { float s, c; __sincosf(-6.283185307179586f * (float)l / 512.0f, &s, &c); Wl = make_float2(c, s); }
  float2 W2l = csqr(Wl), W4l = csqr(W2l);
  float2 W2li = make_float2(W2l.y, -W2l.x);
  float2 T01 = cmulf(Wl, make_float2(H, -H));
  float2 T02 = make_float2(Wl.y, -Wl.x);
  float2 T03 = cmulf(Wl, make_float2(-H, -H));
  float2 t3 = csqr(W4l); if (l & 32) t3 = cneg(t3);
  float2 t4 = csqr(t3);  if (l & 16) t4 = cneg(t4);
  float2 t5 = csqr(t4);  if (l & 8)  t5 = cneg(t5);
  float2 t6 = csqr(t5);  if (l & 4)  t6 = cneg(t6);
  float2 t7 = csqr(t6);  if (l & 2)  t7 = cneg(t7);

  // ---- both pixels of this wave, interleaved (R7-verified math) ----
  int pA = p_base + 2 * w, pB = pA + 1;
  int btA = pA / HWN, hwA = pA - btA * HWN;
  int btB = pB / HWN, hwB = pB - btB * HWN;
  float2* rowA = (float2*)(tile + (2 * w) * TS);
  float2* rowB = (float2*)(tile + (2 * w + 1) * TS);

  float2 z[2][8];
#pragma unroll
  for (int r = 0; r < 8; ++r) { z[0][r] = rowA[l + 64 * r]; z[1][r] = rowB[l + 64 * r]; }

  // ---- forward DIF: in-lane st0..2 ----
  {
    float2 T0[4] = {Wl, T01, T02, T03};
#pragma unroll
    for (int q = 0; q < 2; ++q)
#pragma unroll
      for (int r = 0; r < 4; ++r) {
        float2 a = z[q][r], b = z[q][r + 4];
        z[q][r] = cadd(a, b);
        z[q][r + 4] = cmulf(csub(a, b), T0[r]);
      }
  }
#pragma unroll
  for (int q = 0; q < 2; ++q)
#pragma unroll
    for (int h = 0; h < 2; ++h) {
      int b0 = h * 4;
      float2 a = z[q][b0], b = z[q][b0 + 2];
      z[q][b0] = cadd(a, b); z[q][b0 + 2] = cmulf(csub(a, b), W2l);
      a = z[q][b0 + 1]; b = z[q][b0 + 3];
      z[q][b0 + 1] = cadd(a, b); z[q][b0 + 3] = cmulf(csub(a, b), W2li);
    }
#pragma unroll
  for (int q = 0; q < 2; ++q)
#pragma unroll
    for (int r = 0; r < 8; r += 2) {
      float2 a = z[q][r], b = z[q][r + 1];
      z[q][r] = cadd(a, b); z[q][r + 1] = cmulf(csub(a, b), W4l);
    }
  // st3..8: cross-lane, masks 32,16,8,4,2,1 — pixels interleaved
  {
    float2 tws[6] = {t3, t4, t5, t6, t7, make_float2(1.f, 0.f)};
    int masks[6] = {32, 16, 8, 4, 2, 1};
#pragma unroll
    for (int s = 0; s < 6; ++s) {
      int m = masks[s];
      bool up = (l & m) != 0;
      float2 te = up ? tws[s] : make_float2(1.f, 0.f);
#pragma unroll
      for (int r = 0; r < 8; ++r)
#pragma unroll
        for (int q = 0; q < 2; ++q) {
          float2 v = z[q][r];
          float2 o = make_float2(__shfl_xor(v.x, m, 64), __shfl_xor(v.y, m, 64));
          float2 d = up ? csub(o, v) : cadd(v, o);
          z[q][r] = cmulf(d, te);
        }
    }
  }

  // ---- middle: spill PADDED (phi16), unpack*filter*repack both pixels, reload ----
#pragma unroll
  for (int r = 0; r < 8; ++r) {
    int pidx = l + (l >> 4) + 68 * r;      // phi16(l + 64r)
    rowA[pidx] = z[0][r]; rowB[pidx] = z[1][r];
  }
  {
    const float* wfA = wfilt + (size_t)((btA & 7) * HWN + hwA) * 1026;
    const float* wfB = wfilt + (size_t)((btB & 7) * HWN + hwB) * 1026;
    const float sc = 1.0f / 512.0f;
#pragma unroll
    for (int i = 0; i < 4; ++i) {
      int f = 64 * i + l;
      if (f == 0) {
        // phi16(0)=0, phi16(1)=1
        {
          float2 z0 = rowA[0];
          float X0 = z0.x + z0.y, X512 = z0.x - z0.y;
          float Y0 = X0 * wfA[0] * sc;
          float Y512 = X512 * wfA[1024] * sc;
          rowA[0] = make_float2(0.5f * (Y0 + Y512), 0.5f * (Y0 - Y512));
          float2 z2 = rowA[1];
          float2 X256 = make_float2(z2.x, -z2.y);
          float2 Y = cmulf(X256, make_float2(wfA[512], wfA[513]));
          rowA[1] = make_float2(Y.x * sc, -Y.y * sc);
        }
        {
          float2 z0 = rowB[0];
          float X0 = z0.x + z0.y, X512 = z0.x - z0.y;
          float Y0 = X0 * wfB[0] * sc;
          float Y512 = X512 * wfB[1024] * sc;
          rowB[0] = make_float2(0.5f * (Y0 + Y512), 0.5f * (Y0 - Y512));
          float2 z2 = rowB[1];
          float2 X256 = make_float2(z2.x, -z2.y);
          float2 Y = cmulf(X256, make_float2(wfB[512], wfB[513]));
          rowB[1] = make_float2(Y.x * sc, -Y.y * sc);
        }
      } else {
        int g = 512 - f;
        int pf = (int)(__brev((unsigned)f) >> 23);
        int pg = (int)(__brev((unsigned)g) >> 23);
        int pf2 = pf + (pf >> 4), pg2 = pg + (pg >> 4);   // phi16
        float2 Wf = tw10s[f];
        float2 Wfc = make_float2(Wf.x, -Wf.y);
#pragma unroll
        for (int q = 0; q < 2; ++q) {
          float2* zq = q ? rowB : rowA;
          const float* wf = q ? wfB : wfA;
          float2 Zf = zq[pf2], Zg = zq[pg2];
          float2 A = make_float2(0.5f * (Zf.x + Zg.x), 0.5f * (Zf.y - Zg.y));
          float2 B = make_float2(0.5f * (Zf.y + Zg.y), -0.5f * (Zf.x - Zg.x));
          float2 WB = cmulf(Wf, B);
          float2 Xf = make_float2(A.x + WB.x, A.y + WB.y);
          float2 Xg = make_float2(A.x - WB.x, -(A.y - WB.y));
          float2 Yf = cmulf(Xf, make_float2(wf[2 * f], wf[2 * f + 1]));
          float2 Yg = cmulf(Xg, make_float2(wf[2 * g], wf[2 * g + 1]));
          Yf.x *= sc; Yf.y *= sc; Yg.x *= sc; Yg.y *= sc;
          float2 Ap = make_float2(0.5f * (Yf.x + Yg.x), 0.5f * (Yf.y - Yg.y));
          float2 T  = make_float2(0.5f * (Yf.x - Yg.x), 0.5f * (Yf.y + Yg.y));
          float2 Bp = cmulf(Wfc, T);
          zq[pf2] = make_float2(Ap.x - Bp.y, Ap.y + Bp.x);
          zq[pg2] = make_float2(Ap.x + Bp.y, Bp.x - Ap.y);
        }
      }
    }
  }
#pragma unroll
  for (int r = 0; r < 8; ++r) {
    int pidx = l + (l >> 4) + 68 * r;
    z[0][r] = rowA[pidx]; z[1][r] = rowB[pidx];
  }

  // ---- inverse DIT: cross-lane stages (interleaved) ----
  {
    float2 tws[6] = {make_float2(1.f, 0.f), t7, t6, t5, t4, t3};
    int masks[6] = {1, 2, 4, 8, 16, 32};
#pragma unroll
    for (int s = 0; s < 6; ++s) {
      int m = masks[s];
      bool up = (l & m) != 0;
      float2 te = up ? make_float2(tws[s].x, -tws[s].y) : make_float2(1.f, 0.f);
#pragma unroll
      for (int r = 0; r < 8; ++r)
#pragma unroll
        for (int q = 0; q < 2; ++q) {
          float2 v = cmulf(z[q][r], te);
          float2 o = make_float2(__shfl_xor(v.x, m, 64), __shfl_xor(v.y, m, 64));
          z[q][r] = up ? csub(o, v) : cadd(v, o);
        }
    }
  }
  // inv st2
#pragma unroll
  for (int q = 0; q < 2; ++q)
#pragma unroll
    for (int r = 0; r < 8; r += 2) {
      float2 v = cmulc(z[q][r + 1], W4l);
      float2 a = z[q][r];
      z[q][r] = cadd(a, v); z[q][r + 1] = csub(a, v);
    }
  // inv st1
#pragma unroll
  for (int q = 0; q < 2; ++q)
#pragma unroll
    for (int h = 0; h < 2; ++h) {
      int b0 = h * 4;
      float2 v = cmulc(z[q][b0 + 2], W2l);
      float2 a = z[q][b0];
      z[q][b0] = cadd(a, v); z[q][b0 + 2] = csub(a, v);
      v = cmulc(z[q][b0 + 3], W2li);
      a = z[q][b0 + 1];
      z[q][b0 + 1] = cadd(a, v); z[q][b0 + 3] = csub(a, v);
    }
  // inv st0
  {
    float2 T0[4] = {Wl, T01, T02, T03};
#pragma unroll
    for (int q = 0; q < 2; ++q)
#pragma unroll
      for (int r = 0; r < 4; ++r) {
        float2 v = cmulc(z[q][r + 4], T0[r]);
        float2 a = z[q][r];
        z[q][r] = cadd(a, v); z[q][r + 4] = csub(a, v);
      }
  }

  // ---- pack bf16, store both d rows coalesced ----
  unsigned* dstA = (unsigned*)(dmat + (size_t)pA * CCH);
  unsigned* dstB = (unsigned*)(dmat + (size_t)pB * CCH);
#pragma unroll
  for (int r = 0; r < 8; ++r) {
    float2 vA = z[0][r], vB = z[1][r];
    dstA[l + 64 * r] = (unsigned)f2bf(vA.x) | ((unsigned)f2bf(vA.y) << 16);
    dstB[l + 64 * r] = (unsigned)f2bf(vB.x) | ((unsigned)f2bf(vB.y) << 16);
  }
}

// ---------------------------------------------------------------- stage 2: GEMM + GELU + residual
// R12/R13 verbatim (128x128, BK=32, 8 waves 64px x 32ch, acc[2][4], counted
// vmcnt(2), 2-way both-sides swizzle, 3 blocks/CU; coalesced LDS-transpose
// epilogue with float4 loads/stores over 64 consecutive pixels).
#define GLOAD16(gsrc, ldst)                                                     \
  __builtin_amdgcn_global_load_lds(                                             \
      (const __attribute__((address_space(1))) unsigned int*)(gsrc),            \
      (__attribute__((address_space(3))) unsigned int*)(ldst), 16, 0, 0)

__global__ __launch_bounds__(512) void gemm_gelu_kernel(
    const unsigned short* __restrict__ A,   // d bf16 [NPIX][1024]
    const unsigned short* __restrict__ Bw,  // conv_w bf16 [o][c]
    const float* __restrict__ bias,
    const float* __restrict__ x,
    float* __restrict__ out) {
  __shared__ unsigned short SH[16384];      // 32 KB: lA [0,8192), lB [8192,16384)
  unsigned short* lA = SH;
  unsigned short* lB = SH + 8192;

  int bid = blockIdx.x;
  int j = (bid & 7) * 196 + (bid >> 3);
  int mt = j >> 3, nt = j & 7;          // 196 px-tiles x 8 ch-tiles
  int p0 = mt * 128, n0 = nt * 128;

  int tid = threadIdx.x;
  int l = tid & 63, wid = tid >> 6;
  int wr = wid >> 2, wc = wid & 3;      // wave tile: px p0+wr*64, ch n0+wc*32
  int lr = l & 15, lg = l >> 4;

  f32x4 acc[2][4];   // [ch frag][px frag] = 32 AGPR
#pragma unroll
  for (int i = 0; i < 2; ++i)
#pragma unroll
    for (int jj = 0; jj < 4; ++jj) acc[i][jj] = f32x4{0.f, 0.f, 0.f, 0.f};

  int arow = tid >> 2;
  int acg = (tid & 3) ^ ((tid >> 3) & 3);
  const unsigned short* agA = A  + (size_t)(p0 + arow) * CCH + acg * 8;
  const unsigned short* agB = Bw + (size_t)(n0 + arow) * CCH + acg * 8;
  unsigned short* laW = lA + wid * 512;
  unsigned short* lbW = lB + wid * 512;

  int kx = ((lg ^ ((lr >> 1) & 3)) << 3);
  const unsigned short* lAf0 = lA + (wr * 64 + lr) * 32 + kx;
  const unsigned short* lBf0 = lB + (wc * 32 + lr) * 32 + kx;

#define STAGE(buf, kt)                                                          \
  do {                                                                          \
    GLOAD16(agA + (kt) * 32, laW + (buf) * 4096);                               \
    GLOAD16(agB + (kt) * 32, lbW + (buf) * 4096);                               \
  } while (0)

  STAGE(0, 0);
  __builtin_amdgcn_sched_barrier(0);
  asm volatile("s_waitcnt vmcnt(0)" ::: "memory");
  __builtin_amdgcn_s_barrier();
  __builtin_amdgcn_sched_barrier(0);

  int cur = 0;
#pragma unroll 2
  for (int kk = 0; kk < 32; ++kk) {
    STAGE(cur ^ 1, (kk + 1) & 31);      // prefetch next tile (wrap: dead re-stage)
    __builtin_amdgcn_sched_barrier(0);
    asm volatile("s_waitcnt vmcnt(2)" ::: "memory");   // current tile's 2 landed
    __builtin_amdgcn_s_barrier();
    __builtin_amdgcn_sched_barrier(0);

    short8 af[4], bf[2];
    const unsigned short* lAf = lAf0 + cur * 4096;
    const unsigned short* lBf = lBf0 + cur * 4096;
#pragma unroll
    for (int m = 0; m < 4; ++m) af[m] = *(const short8*)(lAf + m * 512);
#pragma unroll
    for (int n = 0; n < 2; ++n) bf[n] = *(const short8*)(lBf + n * 512);
    __builtin_amdgcn_s_setprio(1);
#pragma unroll
    for (int i = 0; i < 2; ++i)         // ch frags (W rows as M)
#pragma unroll
      for (int jj = 0; jj < 4; ++jj)    // px frags (d rows as N)
        acc[i][jj] = __builtin_amdgcn_mfma_f32_16x16x32_bf16(bf[i], af[jj], acc[i][jj], 0, 0, 0);
    __builtin_amdgcn_s_setprio(0);
    __builtin_amdgcn_sched_barrier(0);
    __builtin_amdgcn_s_barrier();       // reads done -> cur re-stageable
    __builtin_amdgcn_sched_barrier(0);
    cur ^= 1;
  }
#undef STAGE
  asm volatile("s_waitcnt vmcnt(0)" ::: "memory");     // drain wrap-stage leftovers
  __syncthreads();   // ALL waves' dead wrap-stage LDS writes landed -> LDS reusable

  // ---- coalesced epilogue via per-wave LDS transpose ----
  float* tp = (float*)SH + wid * 544;
  int pxb = p0 + wr * 64 + (l & 15) * 4;          // 4-px group (4|196: no row cross)
  int btE = pxb / HWN, hwE = pxb - btE * HWN;
  size_t ebase = (size_t)btE * BTSTR + hwE;       // + ch*HWN per channel

#pragma unroll
  for (int i = 0; i < 2; ++i) {
#pragma unroll
    for (int rr = 0; rr < 2; ++rr) {
#pragma unroll
      for (int jj = 0; jj < 4; ++jj) {
#pragma unroll
        for (int s = 0; s < 2; ++s)
          tp[(lg * 2 + s) * 68 + jj * 16 + lr] = acc[i][jj][2 * rr + s];
      }
      asm volatile("s_waitcnt lgkmcnt(0)" ::: "memory");
      __builtin_amdgcn_sched_barrier(0);
#pragma unroll
      for (int cb = 0; cb < 8; cb += 4) {
        int ct = cb + (l >> 4);
        f32x4 v4 = *(const f32x4*)(tp + ct * 68 + (l & 15) * 4);
        int ch = n0 + wc * 32 + i * 16 + ((ct >> 1) << 2) + 2 * rr + (ct & 1);
        size_t idx = ebase + (size_t)ch * HWN;
        float4 xv = *(const float4*)(x + idx);
        float bc = bias[ch];
        float4 ov;
        {
          float v0 = v4[0] + bc, v1 = v4[1] + bc, v2 = v4[2] + bc, v3 = v4[3] + bc;
          ov.x = xv.x + 0.5f * v0 * (1.0f + erff(v0 * 0.70710678118654752f));
          ov.y = xv.y + 0.5f * v1 * (1.0f + erff(v1 * 0.70710678118654752f));
          ov.z = xv.z + 0.5f * v2 * (1.0f + erff(v2 * 0.70710678118654752f));
          ov.w = xv.w + 0.5f * v3 * (1.0f + erff(v3 * 0.70710678118654752f));
        }
        *(float4*)(out + idx) = ov;
      }
      __builtin_amdgcn_sched_barrier(0);   // keep passes ordered (LDS reuse)
    }
  }
}

// ---------------------------------------------------------------- launcher
extern "C" void kernel_launch(void* const* d_in, const int* in_sizes, int n_in,
                              void* d_out, int out_size, void* d_ws, size_t ws_size,
                              hipStream_t stream) {
  const float* x      = (const float*)d_in[0];
  const float* wfilt  = (const float*)d_in[1];
  const float* conv_w = (const float*)d_in[2];
  const float* conv_b = (const float*)d_in[3];
  char* ws = (char*)d_ws;
  unsigned short* dmat = (unsigned short*)(ws + WS_D);
  unsigned short* bw   = (unsigned short*)(ws + WS_BW);
  float* out           = (float*)d_out;

  wcast_kernel<<<1024, 256, 0, stream>>>(conv_w, bw);
  fft_filter_kernel<<<3136, 256, 0, stream>>>(x, wfilt, dmat);
  gemm_gelu_kernel<<<1568, 512, 0, stream>>>(dmat, bw, conv_b, x, out);
}